// Round 1
// baseline (9637.835 us; speedup 1.0000x reference)
//
#include <hip/hip_runtime.h>
#include <cmath>

#define DEV __device__ __forceinline__

// ---------- constants ----------
// B=16, T=96, K=64, D=768, H=400, L=3, M=500
// BT = 1536, 4H = 1600, both dirs = 3200, 2H = 800

DEV float wred_max(float v){ for(int o=32;o;o>>=1) v=fmaxf(v,__shfl_xor(v,o)); return v; }
DEV float wred_sum(float v){ for(int o=32;o;o>>=1) v+=__shfl_xor(v,o); return v; }
DEV float sigf(float x){ return 1.f/(1.f+expf(-x)); }

// ---------- embedding gather ----------
__global__ __launch_bounds__(256) void embed_kern(const float* __restrict__ tab,
                                                  const int* __restrict__ labels,
                                                  float* __restrict__ x0){
  long idx = (long)blockIdx.x*256 + threadIdx.x;   // BT*768
  if (idx >= 1536L*768) return;
  int m = (int)(idx/768), d = (int)(idx%768);
  x0[idx] = tab[(long)labels[m]*768 + d];
}

// ---------- transpose whh[l] (2,1600,400) -> (2,400,1600) ----------
__global__ __launch_bounds__(256) void trans_whh(const float* __restrict__ whh,
                                                 float* __restrict__ wT, int l){
  int idx = blockIdx.x*256 + threadIdx.x;          // 1,280,000
  if (idx >= 1280000) return;
  int row = idx % 1600;
  int k   = (idx/1600) % 400;
  int dir = idx/640000;
  wT[idx] = whh[(long)l*1280000 + (long)dir*640000 + (long)row*400 + k];
}

// ---------- transpose biaffine 500x500 ----------
__global__ __launch_bounds__(256) void trans_sq(const float* __restrict__ w,
                                                float* __restrict__ wt){
  int idx = blockIdx.x*256 + threadIdx.x;          // 250,000
  if (idx >= 250000) return;
  int j = idx/500, i = idx%500;
  wt[idx] = w[(long)i*500 + j];                    // wt[j][i] = w[i][j]
}

// ---------- generic fp32 GEMM: C[m,n] = sum_k A[m,k]*B[n,k] (+bias, leaky) ----------
// A: M x K (ld=K), B: N x K (ld=K), C: M x N (ld=N). blockIdx.z batches via strides.
__global__ __launch_bounds__(256) void gemm_abt(const float* __restrict__ A,
                                                const float* __restrict__ Bm,
                                                float* __restrict__ C,
                                                const float* __restrict__ bias,
                                                int M, int N, int K,
                                                long sA, long sB, long sC, int leaky){
  A  += (long)blockIdx.z * sA;
  Bm += (long)blockIdx.z * sB;
  C  += (long)blockIdx.z * sC;
  __shared__ float As[16][68];
  __shared__ float Bs[16][68];
  int tid = threadIdx.x;
  int tx = tid & 15, ty = tid >> 4;
  int m0 = blockIdx.x * 64, n0 = blockIdx.y * 64;
  int lrow = tid >> 2, lc = (tid & 3) * 4;
  float acc[4][4] = {};
  for (int k0 = 0; k0 < K; k0 += 16) {
    #pragma unroll
    for (int u = 0; u < 4; u++) {
      int k = k0 + lc + u;
      int am = m0 + lrow;
      As[lc+u][lrow] = (am < M && k < K) ? A[(long)am*K + k] : 0.f;
      int bn = n0 + lrow;
      Bs[lc+u][lrow] = (bn < N && k < K) ? Bm[(long)bn*K + k] : 0.f;
    }
    __syncthreads();
    #pragma unroll
    for (int kk = 0; kk < 16; kk++) {
      float a[4], bb[4];
      #pragma unroll
      for (int u=0;u<4;u++){ a[u]=As[kk][ty*4+u]; bb[u]=Bs[kk][tx*4+u]; }
      #pragma unroll
      for (int i=0;i<4;i++)
        #pragma unroll
        for (int j=0;j<4;j++) acc[i][j] = fmaf(a[i], bb[j], acc[i][j]);
    }
    __syncthreads();
  }
  #pragma unroll
  for (int i=0;i<4;i++){
    int m = m0 + ty*4 + i;
    if (m >= M) continue;
    #pragma unroll
    for (int j=0;j<4;j++){
      int n = n0 + tx*4 + j;
      if (n >= N) continue;
      float v = acc[i][j];
      if (bias) v += bias[n];
      if (leaky) v = v > 0.f ? v : 0.1f*v;
      C[(long)m*N + n] = v;
    }
  }
}

// ---------- one LSTM timestep, both directions ----------
// G: 1536 x 3200 precomputed x@Wih^T + bias. WT: [dir][k][1600].
// hprev/hnext/c: [dir][b][400]. xout: 1536 x 800 (concat fwd|bwd).
__global__ __launch_bounds__(256) void lstm_step(const float* __restrict__ G,
                                                 const float* __restrict__ WT,
                                                 const float* __restrict__ hprev,
                                                 float* __restrict__ hnext,
                                                 float* __restrict__ cbuf,
                                                 float* __restrict__ xout, int s){
  int tid = blockIdx.x*256 + threadIdx.x;      // 0..12799
  int dir = tid / 6400;
  int r   = tid - dir*6400;
  int b   = r / 400;
  int jj  = r - b*400;
  int t   = dir ? (95 - s) : s;
  const float* g = G + (long)(b*96 + t)*3200 + dir*1600 + jj;
  float ai = g[0], af = g[400], ag = g[800], ao = g[1200];
  const float* w  = WT + (long)dir*640000 + jj;
  const float* hp = hprev + dir*6400 + b*400;
  #pragma unroll 8
  for (int k = 0; k < 400; k++) {
    float hk = hp[k];
    const float* wr = w + k*1600;
    ai = fmaf(hk, wr[0],    ai);
    af = fmaf(hk, wr[400],  af);
    ag = fmaf(hk, wr[800],  ag);
    ao = fmaf(hk, wr[1200], ao);
  }
  int ci = dir*6400 + b*400 + jj;
  float cv = cbuf[ci];
  cv = sigf(af)*cv + sigf(ai)*tanhf(ag);
  float hv = sigf(ao)*tanhf(cv);
  cbuf[ci]  = cv;
  hnext[ci] = hv;
  xout[(long)(b*96 + t)*800 + dir*400 + jj] = hv;
}

// ---------- log_softmax over last axis of s_arc, write transposed p ----------
__global__ __launch_bounds__(256) void softmax_p(const float* __restrict__ sarc,
                                                 float* __restrict__ p){
  int row  = blockIdx.x*4 + (threadIdx.x >> 6);  // 0..1535  (b,x)
  int lane = threadIdx.x & 63;
  int b = row/96, x = row%96;
  const float* s = sarc + (long)(b*96 + x)*96;
  float v1 = s[lane];
  float v2 = (lane+64 < 96) ? s[lane+64] : -INFINITY;
  float mx = wred_max(fmaxf(v1,v2));
  float sm = wred_sum(expf(v1-mx) + expf(v2-mx));
  float lse = mx + logf(sm);
  float* pr = p + (long)b*9216;
  pr[lane*96 + x] = v1 - lse;
  if (lane+64 < 96) pr[(lane+64)*96 + x] = v2 - lse;
}

// ---------- best_score ----------
__global__ __launch_bounds__(128) void best_kern(const float* __restrict__ p,
                                                 const float* __restrict__ multinomial,
                                                 const int* __restrict__ labels,
                                                 const int* __restrict__ heads,
                                                 float* __restrict__ best){
  int b = blockIdx.x, tid = threadIdx.x;
  float acc = 0.f;
  for (int ti = tid; ti < 95; ti += 128) {
    int y = heads[b*95 + ti];
    int x = ti + 1;
    acc += p[(long)b*9216 + y*96 + x]
         + multinomial[(long)labels[b*96 + y]*64 + labels[b*96 + x]];
  }
  acc = wred_sum(acc);
  __shared__ float tmp[2];
  if ((tid & 63) == 0) tmp[tid >> 6] = acc;
  __syncthreads();
  if (tid == 0) best[b] = tmp[0] + tmp[1];
}

// ---------- Eisner inside algorithm, one block per batch element ----------
// LDS Cp: C_r at [i][j] (i<=j), C_l[i][j] stored at [j][i]. Diagonal shared (=0).
// Global Ip: I_r[i][j] at i*96+j, I_l[i][j] at j*96+i.
__global__ __launch_bounds__(1024) void inside_kern(const float* __restrict__ p,
                                                    float* __restrict__ Ipg,
                                                    float* __restrict__ part){
  __shared__ float Cp[96][97];
  int b = blockIdx.x;
  const float* pB = p + (long)b*9216;
  float* Ip = Ipg + (long)b*9216;
  int tid = threadIdx.x;
  for (int idx = tid; idx < 96*97; idx += 1024) {
    int row = idx/97, col = idx%97;
    Cp[row][col] = (row == col) ? 0.f : -1e9f;
  }
  __syncthreads();
  int wave = tid >> 6, lane = tid & 63;
  for (int w = 1; w < 96; w++) {
    for (int i = wave; i < 96 - w; i += 16) {
      int j = i + w;
      // inc = lse_{r=0..w-1} C_r[i][i+r] + C_l[i+r+1][j]
      float v1 = -INFINITY, v2 = -INFINITY;
      if (lane < w)    v1 = Cp[i][i+lane]    + Cp[j][i+1+lane];
      if (lane+64 < w) v2 = Cp[i][i+64+lane] + Cp[j][i+65+lane];
      float mx = wred_max(fmaxf(v1,v2));
      float sm = wred_sum(expf(v1-mx) + expf(v2-mx));
      float inc = mx + logf(sm);
      float ir = inc + pB[i*96 + j];
      float il = inc + pB[j*96 + i];
      if (lane == 0) { Ip[i*96 + j] = ir; Ip[j*96 + i] = il; }
      // cr = lse_{rr=1..w} I_r[i][i+rr] + C_r[i+rr][j]   (rr=w term = ir + 0)
      int rr1 = lane+1, rr2 = lane+65;
      v1 = (rr1 < w) ? Ip[i*96 + i + rr1] + Cp[i+rr1][j] : (rr1 == w ? ir : -INFINITY);
      v2 = (rr2 < w) ? Ip[i*96 + i + rr2] + Cp[i+rr2][j] : (rr2 == w ? ir : -INFINITY);
      mx = wred_max(fmaxf(v1,v2));
      sm = wred_sum(expf(v1-mx) + expf(v2-mx));
      float cr = mx + logf(sm);
      // cl = lse_{r=0..w-1} C_l[i][i+r] + I_l[i+r][j]    (r=0 term = 0 + il)
      int r1 = lane, r2 = lane+64;
      v1 = (r1 == 0) ? il : ((r1 < w) ? Cp[i+r1][i] + Ip[j*96 + i + r1] : -INFINITY);
      v2 = (r2 < w) ? Cp[i+r2][i] + Ip[j*96 + i + r2] : -INFINITY;
      mx = wred_max(fmaxf(v1,v2));
      sm = wred_sum(expf(v1-mx) + expf(v2-mx));
      float cl = mx + logf(sm);
      if (lane == 0) { Cp[i][j] = cr; Cp[j][i] = cl; }
    }
    __syncthreads();
  }
  if (tid == 0) part[b] = Cp[0][95];
}

// ---------- final mean ----------
__global__ __launch_bounds__(64) void final_kern(const float* __restrict__ part,
                                                 const float* __restrict__ best,
                                                 float* __restrict__ out){
  int lane = threadIdx.x;
  float v = (lane < 16) ? part[lane] - best[lane] : 0.f;
  v = wred_sum(v);
  if (lane == 0) out[0] = v * (1.f/16.f);
}

extern "C" void kernel_launch(void* const* d_in, const int* in_sizes, int n_in,
                              void* d_out, int out_size, void* d_ws, size_t ws_size,
                              hipStream_t stream) {
  const float* emb   = (const float*)d_in[0];
  const float* multi = (const float*)d_in[1];
  const float* wih0  = (const float*)d_in[2];
  const float* wih   = (const float*)d_in[3];
  const float* whh   = (const float*)d_in[4];
  const float* bias  = (const float*)d_in[5];
  const float* mhw   = (const float*)d_in[6];
  const float* mhb   = (const float*)d_in[7];
  const float* mdw   = (const float*)d_in[8];
  const float* mdb   = (const float*)d_in[9];
  const float* biaf  = (const float*)d_in[10];
  const int*   labels= (const int*)d_in[11];
  const int*   heads = (const int*)d_in[12];
  float* out = (float*)d_out;

  float* ws = (float*)d_ws;
  size_t off = 0;
  auto alloc = [&](size_t n){ float* q = ws + off; off += n; return q; };
  float* G    = alloc(1536L*3200);
  float* x0   = alloc(1536L*768);
  float* xA   = alloc(1536L*800);
  float* xB   = alloc(1536L*800);
  float* WT   = alloc(2L*400*1600);
  float* WTb  = alloc(500L*500);
  float* arcH = alloc(1536L*500);
  float* arcD = alloc(1536L*500);
  float* tmp  = alloc(1536L*500);
  float* sarc = alloc(16L*96*96);
  float* pbuf = alloc(16L*96*96);
  float* Ip   = alloc(16L*96*96);
  float* hbuf = alloc(2L*12800);
  float* cbuf = alloc(12800);
  float* part = alloc(16);
  float* best = alloc(16);
  (void)ws_size; (void)in_sizes; (void)n_in; (void)out_size;

  embed_kern<<<(1536*768)/256, 256, 0, stream>>>(emb, labels, x0);
  trans_sq<<<(250000+255)/256, 256, 0, stream>>>(biaf, WTb);

  const float* xin = x0;
  float* xout = xA;
  for (int l = 0; l < 3; l++) {
    int Kd = (l==0) ? 768 : 800;
    const float* W = (l==0) ? wih0 : wih + (size_t)(l-1)*2*1600*800;
    dim3 gp(24, 50, 1);
    gemm_abt<<<gp, 256, 0, stream>>>(xin, W, G, bias + l*3200, 1536, 3200, Kd, 0,0,0, 0);
    trans_whh<<<1280000/256, 256, 0, stream>>>(whh, WT, l);
    hipMemsetAsync(hbuf, 0, 12800*sizeof(float), stream);
    hipMemsetAsync(cbuf, 0, 12800*sizeof(float), stream);
    for (int s = 0; s < 96; s++) {
      lstm_step<<<50, 256, 0, stream>>>(G, WT, hbuf + (s&1)*12800,
                                        hbuf + ((s+1)&1)*12800, cbuf, xout, s);
    }
    xin = xout;
    xout = (l==0) ? xB : xA;
  }
  // xin == xA (l0:x0->xA, l1:xA->xB, l2:xB->xA)
  dim3 gm(24, 8, 1);
  gemm_abt<<<gm, 256, 0, stream>>>(xin,  mhw, arcH, mhb, 1536, 500, 800, 0,0,0, 1);
  gemm_abt<<<gm, 256, 0, stream>>>(xin,  mdw, arcD, mdb, 1536, 500, 800, 0,0,0, 1);
  gemm_abt<<<gm, 256, 0, stream>>>(arcD, WTb, tmp, nullptr, 1536, 500, 500, 0,0,0, 0);
  dim3 gs(2, 2, 16);
  gemm_abt<<<gs, 256, 0, stream>>>(tmp, arcH, sarc, nullptr, 96, 96, 500,
                                   96L*500, 96L*500, 96L*96, 0);
  softmax_p<<<384, 256, 0, stream>>>(sarc, pbuf);
  best_kern<<<16, 128, 0, stream>>>(pbuf, multi, labels, heads, best);
  inside_kern<<<16, 1024, 0, stream>>>(pbuf, Ip, part);
  final_kern<<<1, 64, 0, stream>>>(part, best, out);
}

// Round 3
// 9230.994 us; speedup vs baseline: 1.0441x; 1.0441x over previous
//
#include <hip/hip_runtime.h>
#include <cmath>

#define DEV __device__ __forceinline__

// ---------- constants ----------
// B=16, T=96, K=64, D=768, H=400, L=3, M=500
// BT = 1536, 4H = 1600, both dirs = 3200, 2H = 800
// NOTE: the LSTM stack is chaotic (||Whh||~6): everything feeding the
// recurrence (G gemm, weights, h) must be fp32-exact. fp16 weights failed
// with absmax 1355 (round 2).

DEV float wred_max(float v){ for(int o=32;o;o>>=1) v=fmaxf(v,__shfl_xor(v,o)); return v; }
DEV float wred_sum(float v){ for(int o=32;o;o>>=1) v+=__shfl_xor(v,o); return v; }
DEV float sigf(float x){ return 1.f/(1.f+__expf(-x)); }

// ---------- embedding gather ----------
__global__ __launch_bounds__(256) void embed_kern(const float* __restrict__ tab,
                                                  const int* __restrict__ labels,
                                                  float* __restrict__ x0){
  long idx = (long)blockIdx.x*256 + threadIdx.x;   // BT*768
  if (idx >= 1536L*768) return;
  int m = (int)(idx/768), d = (int)(idx%768);
  x0[idx] = tab[(long)labels[m]*768 + d];
}

// ---------- whh[l] (2,1600,400) -> WK4 [dir][k4][r] float4 (k4=0..99) ----------
__global__ __launch_bounds__(256) void make_wk4(const float* __restrict__ whh,
                                                float4* __restrict__ wk4, int l){
  int idx = blockIdx.x*256 + threadIdx.x;          // 2*100*1600 = 320,000
  if (idx >= 320000) return;
  int r   = idx % 1600;
  int k4  = (idx/1600) % 100;
  int dir = idx / 160000;
  const float* src = whh + ((size_t)(l*2+dir)*1600 + r)*400 + 4*k4;
  wk4[idx] = *(const float4*)src;
}

// ---------- transpose biaffine 500x500 ----------
__global__ __launch_bounds__(256) void trans_sq(const float* __restrict__ w,
                                                float* __restrict__ wt){
  int idx = blockIdx.x*256 + threadIdx.x;          // 250,000
  if (idx >= 250000) return;
  int j = idx/500, i = idx%500;
  wt[idx] = w[(long)i*500 + j];                    // wt[j][i] = w[i][j]
}

// ---------- generic fp32 GEMM: C[m,n] = sum_k A[m,k]*B[n,k] (+bias, leaky) ----------
__global__ __launch_bounds__(256) void gemm_abt(const float* __restrict__ A,
                                                const float* __restrict__ Bm,
                                                float* __restrict__ C,
                                                const float* __restrict__ bias,
                                                int M, int N, int K,
                                                long sA, long sB, long sC, int leaky){
  A  += (long)blockIdx.z * sA;
  Bm += (long)blockIdx.z * sB;
  C  += (long)blockIdx.z * sC;
  __shared__ float As[16][68];
  __shared__ float Bs[16][68];
  int tid = threadIdx.x;
  int tx = tid & 15, ty = tid >> 4;
  int m0 = blockIdx.x * 64, n0 = blockIdx.y * 64;
  int lrow = tid >> 2, lc = (tid & 3) * 4;
  float acc[4][4] = {};
  for (int k0 = 0; k0 < K; k0 += 16) {
    #pragma unroll
    for (int u = 0; u < 4; u++) {
      int k = k0 + lc + u;
      int am = m0 + lrow;
      As[lc+u][lrow] = (am < M && k < K) ? A[(long)am*K + k] : 0.f;
      int bn = n0 + lrow;
      Bs[lc+u][lrow] = (bn < N && k < K) ? Bm[(long)bn*K + k] : 0.f;
    }
    __syncthreads();
    #pragma unroll
    for (int kk = 0; kk < 16; kk++) {
      float a[4], bb[4];
      #pragma unroll
      for (int u=0;u<4;u++){ a[u]=As[kk][ty*4+u]; bb[u]=Bs[kk][tx*4+u]; }
      #pragma unroll
      for (int i=0;i<4;i++)
        #pragma unroll
        for (int j=0;j<4;j++) acc[i][j] = fmaf(a[i], bb[j], acc[i][j]);
    }
    __syncthreads();
  }
  #pragma unroll
  for (int i=0;i<4;i++){
    int m = m0 + ty*4 + i;
    if (m >= M) continue;
    #pragma unroll
    for (int j=0;j<4;j++){
      int n = n0 + tx*4 + j;
      if (n >= N) continue;
      float v = acc[i][j];
      if (bias) v += bias[n];
      if (leaky) v = v > 0.f ? v : 0.1f*v;
      C[(long)m*N + n] = v;
    }
  }
}

// ---------- persistent fp32 LSTM chain: one block per (dir,batch) ----------
// dir = blockIdx&1 so blockIdx%8 XCD round-robin gives each XCD one
// direction's 2.56MB weight set (fits 4MB L2).
// G: [b][t][3200] = x@Wih^T + bias. WK4: [dir][k4][1600] float4 (W[r][4k4..4k4+3]).
// xout: [b][t][800] (fwd | bwd concat).
__global__ __launch_bounds__(512) void lstm_chain(const float* __restrict__ G,
                                                  const float4* __restrict__ WK4,
                                                  float* __restrict__ xout){
  __shared__ float4 h4s[100];      // h, 400 fp32
  __shared__ float gbuf[1600];
  int tid = threadIdx.x;
  int dir = blockIdx.x & 1, bat = blockIdx.x >> 1;
  const float4* wbase = WK4 + (size_t)dir*160000;
  const float* gbase = G + (size_t)bat*96*3200 + dir*1600;
  float* xo = xout + (size_t)bat*96*800 + dir*400;
  float c = 0.f;
  if (tid < 100) { float4 z = {0.f,0.f,0.f,0.f}; h4s[tid] = z; }
  __syncthreads();
  int r0 = tid, r1 = tid+512, r2 = tid+1024, r3 = tid+1536;
  bool has4 = (tid < 64);
  for (int s = 0; s < 96; s++){
    int t = dir ? (95 - s) : s;
    const float* g = gbase + (size_t)t*3200;
    float a0 = g[r0], a1 = g[r1], a2 = g[r2];
    float a3 = has4 ? g[r3] : 0.f;
    for (int k4 = 0; k4 < 100; k4++){
      float4 h = h4s[k4];                      // broadcast
      const float4* wk = wbase + (size_t)k4*1600;
      float4 w0 = wk[r0], w1 = wk[r1], w2 = wk[r2];
      a0 = fmaf(w0.x,h.x, fmaf(w0.y,h.y, fmaf(w0.z,h.z, fmaf(w0.w,h.w, a0))));
      a1 = fmaf(w1.x,h.x, fmaf(w1.y,h.y, fmaf(w1.z,h.z, fmaf(w1.w,h.w, a1))));
      a2 = fmaf(w2.x,h.x, fmaf(w2.y,h.y, fmaf(w2.z,h.z, fmaf(w2.w,h.w, a2))));
      if (has4) {
        float4 w3 = wk[r3];
        a3 = fmaf(w3.x,h.x, fmaf(w3.y,h.y, fmaf(w3.z,h.z, fmaf(w3.w,h.w, a3))));
      }
    }
    gbuf[r0] = a0; gbuf[r1] = a1; gbuf[r2] = a2;
    if (has4) gbuf[r3] = a3;
    __syncthreads();
    if (tid < 400){
      float ai = gbuf[tid], af = gbuf[tid+400], ag = gbuf[tid+800], ao = gbuf[tid+1200];
      c = sigf(af)*c + sigf(ai)*tanhf(ag);
      float hv = sigf(ao)*tanhf(c);
      ((float*)h4s)[tid] = hv;
      xo[(size_t)t*800 + tid] = hv;
    }
    __syncthreads();
  }
}

// ---------- log_softmax over last axis of s_arc, write transposed p ----------
__global__ __launch_bounds__(256) void softmax_p(const float* __restrict__ sarc,
                                                 float* __restrict__ p){
  int row  = blockIdx.x*4 + (threadIdx.x >> 6);  // 0..1535  (b,x)
  int lane = threadIdx.x & 63;
  int b = row/96, x = row%96;
  const float* s = sarc + (long)(b*96 + x)*96;
  float v1 = s[lane];
  float v2 = (lane+64 < 96) ? s[lane+64] : -INFINITY;
  float mx = wred_max(fmaxf(v1,v2));
  float sm = wred_sum(__expf(v1-mx) + __expf(v2-mx));
  float lse = mx + __logf(sm);
  float* pr = p + (long)b*9216;
  pr[lane*96 + x] = v1 - lse;
  if (lane+64 < 96) pr[(lane+64)*96 + x] = v2 - lse;
}

// ---------- best_score ----------
__global__ __launch_bounds__(128) void best_kern(const float* __restrict__ p,
                                                 const float* __restrict__ multinomial,
                                                 const int* __restrict__ labels,
                                                 const int* __restrict__ heads,
                                                 float* __restrict__ best){
  int b = blockIdx.x, tid = threadIdx.x;
  float acc = 0.f;
  for (int ti = tid; ti < 95; ti += 128) {
    int y = heads[b*95 + ti];
    int x = ti + 1;
    acc += p[(long)b*9216 + y*96 + x]
         + multinomial[(long)labels[b*96 + y]*64 + labels[b*96 + x]];
  }
  acc = wred_sum(acc);
  __shared__ float tmp[2];
  if ((tid & 63) == 0) tmp[tid >> 6] = acc;
  __syncthreads();
  if (tid == 0) best[b] = tmp[0] + tmp[1];
}

// ---------- Eisner inside algorithm, one block per batch element ----------
// LDS Cp: C_r at [i][j] (i<=j), C_l[i][j] at [j][i]. Diagonal shared (=0).
// LDS Ipp: I_r[i][j] at [i][j], I_l[i][j] at [j][i] (strict i<j).
__global__ __launch_bounds__(1024) void inside_kern(const float* __restrict__ p,
                                                    float* __restrict__ part){
  __shared__ float Cp[96][97];
  __shared__ float Ipp[96][97];
  int b = blockIdx.x;
  const float* pB = p + (long)b*9216;
  int tid = threadIdx.x;
  for (int idx = tid; idx < 96*97; idx += 1024) {
    int row = idx/97, col = idx%97;
    Cp[row][col] = (row == col) ? 0.f : -1e9f;
    Ipp[row][col] = -1e9f;
  }
  __syncthreads();
  int wave = tid >> 6, lane = tid & 63;
  for (int w = 1; w < 96; w++) {
    for (int i = wave; i < 96 - w; i += 16) {
      int j = i + w;
      // inc = lse_{r=0..w-1} C_r[i][i+r] + C_l[i+r+1][j]
      float v1 = -INFINITY, v2 = -INFINITY;
      if (lane < w)    v1 = Cp[i][i+lane]    + Cp[j][i+1+lane];
      if (lane+64 < w) v2 = Cp[i][i+64+lane] + Cp[j][i+65+lane];
      float mx = wred_max(fmaxf(v1,v2));
      float sm = wred_sum(__expf(v1-mx) + __expf(v2-mx));
      float inc = mx + __logf(sm);
      float ir = inc + pB[i*96 + j];
      float il = inc + pB[j*96 + i];
      // cr = lse_{rr=1..w} I_r[i][i+rr] + C_r[i+rr][j]   (rr=w term = ir + 0)
      int rr1 = lane+1, rr2 = lane+65;
      v1 = (rr1 < w) ? Ipp[i][i+rr1] + Cp[i+rr1][j] : (rr1 == w ? ir : -INFINITY);
      v2 = (rr2 < w) ? Ipp[i][i+rr2] + Cp[i+rr2][j] : (rr2 == w ? ir : -INFINITY);
      mx = wred_max(fmaxf(v1,v2));
      sm = wred_sum(__expf(v1-mx) + __expf(v2-mx));
      float cr = mx + __logf(sm);
      // cl = lse_{r=0..w-1} C_l[i][i+r] + I_l[i+r][j]    (r=0 term = 0 + il)
      int r1 = lane, r2 = lane+64;
      v1 = (r1 == 0) ? il : ((r1 < w) ? Cp[i+r1][i] + Ipp[j][i+r1] : -INFINITY);
      v2 = (r2 < w) ? Cp[i+r2][i] + Ipp[j][i+r2] : -INFINITY;
      mx = wred_max(fmaxf(v1,v2));
      sm = wred_sum(__expf(v1-mx) + __expf(v2-mx));
      float cl = mx + __logf(sm);
      if (lane == 0) {
        Ipp[i][j] = ir; Ipp[j][i] = il;
        Cp[i][j] = cr;  Cp[j][i] = cl;
      }
    }
    __syncthreads();
  }
  if (tid == 0) part[b] = Cp[0][95];
}

// ---------- final mean ----------
__global__ __launch_bounds__(64) void final_kern(const float* __restrict__ part,
                                                 const float* __restrict__ best,
                                                 float* __restrict__ out){
  int lane = threadIdx.x;
  float v = (lane < 16) ? part[lane] - best[lane] : 0.f;
  v = wred_sum(v);
  if (lane == 0) out[0] = v * (1.f/16.f);
}

extern "C" void kernel_launch(void* const* d_in, const int* in_sizes, int n_in,
                              void* d_out, int out_size, void* d_ws, size_t ws_size,
                              hipStream_t stream) {
  const float* emb   = (const float*)d_in[0];
  const float* multi = (const float*)d_in[1];
  const float* wih0  = (const float*)d_in[2];
  const float* wih   = (const float*)d_in[3];
  const float* whh   = (const float*)d_in[4];
  const float* bias  = (const float*)d_in[5];
  const float* mhw   = (const float*)d_in[6];
  const float* mhb   = (const float*)d_in[7];
  const float* mdw   = (const float*)d_in[8];
  const float* mdb   = (const float*)d_in[9];
  const float* biaf  = (const float*)d_in[10];
  const int*   labels= (const int*)d_in[11];
  const int*   heads = (const int*)d_in[12];
  float* out = (float*)d_out;

  float* ws = (float*)d_ws;
  size_t off = 0;
  auto alloc = [&](size_t n){ float* q = ws + off; off += n; return q; };
  float* G    = alloc(1536L*3200);
  float* x0   = alloc(1536L*768);
  float* xA   = alloc(1536L*800);
  float* xB   = alloc(1536L*800);
  float4* WK4 = (float4*)alloc(1280000);      // 2*100*1600 float4 = 5.12MB
  float* WTb  = alloc(500L*500);
  float* arcH = alloc(1536L*500);
  float* arcD = alloc(1536L*500);
  float* tmp  = alloc(1536L*500);
  float* sarc = alloc(16L*96*96);
  float* pbuf = alloc(16L*96*96);
  float* part = alloc(16);
  float* best = alloc(16);
  (void)ws_size; (void)in_sizes; (void)n_in; (void)out_size;

  embed_kern<<<(1536*768)/256, 256, 0, stream>>>(emb, labels, x0);
  trans_sq<<<(250000+255)/256, 256, 0, stream>>>(biaf, WTb);

  const float* xin = x0;
  float* xout = xA;
  for (int l = 0; l < 3; l++) {
    int Kd = (l==0) ? 768 : 800;
    const float* W = (l==0) ? wih0 : wih + (size_t)(l-1)*2*1600*800;
    dim3 gp(24, 50, 1);
    gemm_abt<<<gp, 256, 0, stream>>>(xin, W, G, bias + l*3200, 1536, 3200, Kd, 0,0,0, 0);
    make_wk4<<<1250, 256, 0, stream>>>(whh, WK4, l);
    lstm_chain<<<32, 512, 0, stream>>>(G, WK4, xout);
    xin = xout;
    xout = (l==0) ? xB : xA;
  }
  // xin == xA (l0:x0->xA, l1:xA->xB, l2:xB->xA)
  dim3 gm(24, 8, 1);
  gemm_abt<<<gm, 256, 0, stream>>>(xin,  mhw, arcH, mhb, 1536, 500, 800, 0,0,0, 1);
  gemm_abt<<<gm, 256, 0, stream>>>(xin,  mdw, arcD, mdb, 1536, 500, 800, 0,0,0, 1);
  gemm_abt<<<gm, 256, 0, stream>>>(arcD, WTb, tmp, nullptr, 1536, 500, 500, 0,0,0, 0);
  dim3 gs(2, 2, 16);
  gemm_abt<<<gs, 256, 0, stream>>>(tmp, arcH, sarc, nullptr, 96, 96, 500,
                                   96L*500, 96L*500, 96L*96, 0);
  softmax_p<<<384, 256, 0, stream>>>(sarc, pbuf);
  best_kern<<<16, 128, 0, stream>>>(pbuf, multi, labels, heads, best);
  inside_kern<<<16, 1024, 0, stream>>>(pbuf, part);
  final_kern<<<1, 64, 0, stream>>>(part, best, out);
}

// Round 4
// 6106.486 us; speedup vs baseline: 1.5783x; 1.5117x over previous
//
#include <hip/hip_runtime.h>
#include <cmath>

#define DEV __device__ __forceinline__

// ---------- constants ----------
// B=16, T=96, K=64, D=768, H=400, L=3, M=500
// BT = 1536, 4H = 1600, both dirs = 3200, 2H = 800
// NOTE: the LSTM stack is chaotic (||Whh||~6): everything feeding the
// recurrence must be fp32-exact. fp16 weights failed with absmax 1355 (r2).

#define NBLK_LSTM 100

DEV float wred_max(float v){ for(int o=32;o;o>>=1) v=fmaxf(v,__shfl_xor(v,o)); return v; }
DEV float wred_sum(float v){ for(int o=32;o;o>>=1) v+=__shfl_xor(v,o); return v; }
DEV float sigf(float x){ return 1.f/(1.f+__expf(-x)); }

// ---------- embedding gather ----------
__global__ __launch_bounds__(256) void embed_kern(const float* __restrict__ tab,
                                                  const int* __restrict__ labels,
                                                  float* __restrict__ x0){
  long idx = (long)blockIdx.x*256 + threadIdx.x;   // BT*768
  if (idx >= 1536L*768) return;
  int m = (int)(idx/768), d = (int)(idx%768);
  x0[idx] = tab[(long)labels[m]*768 + d];
}

// ---------- transpose biaffine 500x500 ----------
__global__ __launch_bounds__(256) void trans_sq(const float* __restrict__ w,
                                                float* __restrict__ wt){
  int idx = blockIdx.x*256 + threadIdx.x;          // 250,000
  if (idx >= 250000) return;
  int j = idx/500, i = idx%500;
  wt[idx] = w[(long)i*500 + j];                    // wt[j][i] = w[i][j]
}

// ---------- generic fp32 GEMM: C[m,n] = sum_k A[m,k]*B[n,k] (+bias, leaky) ----------
__global__ __launch_bounds__(256) void gemm_abt(const float* __restrict__ A,
                                                const float* __restrict__ Bm,
                                                float* __restrict__ C,
                                                const float* __restrict__ bias,
                                                int M, int N, int K,
                                                long sA, long sB, long sC, int leaky){
  A  += (long)blockIdx.z * sA;
  Bm += (long)blockIdx.z * sB;
  C  += (long)blockIdx.z * sC;
  __shared__ float As[16][68];
  __shared__ float Bs[16][68];
  int tid = threadIdx.x;
  int tx = tid & 15, ty = tid >> 4;
  int m0 = blockIdx.x * 64, n0 = blockIdx.y * 64;
  int lrow = tid >> 2, lc = (tid & 3) * 4;
  float acc[4][4] = {};
  for (int k0 = 0; k0 < K; k0 += 16) {
    #pragma unroll
    for (int u = 0; u < 4; u++) {
      int k = k0 + lc + u;
      int am = m0 + lrow;
      As[lc+u][lrow] = (am < M && k < K) ? A[(long)am*K + k] : 0.f;
      int bn = n0 + lrow;
      Bs[lc+u][lrow] = (bn < N && k < K) ? Bm[(long)bn*K + k] : 0.f;
    }
    __syncthreads();
    #pragma unroll
    for (int kk = 0; kk < 16; kk++) {
      float a[4], bb[4];
      #pragma unroll
      for (int u=0;u<4;u++){ a[u]=As[kk][ty*4+u]; bb[u]=Bs[kk][tx*4+u]; }
      #pragma unroll
      for (int i=0;i<4;i++)
        #pragma unroll
        for (int j=0;j<4;j++) acc[i][j] = fmaf(a[i], bb[j], acc[i][j]);
    }
    __syncthreads();
  }
  #pragma unroll
  for (int i=0;i<4;i++){
    int m = m0 + ty*4 + i;
    if (m >= M) continue;
    #pragma unroll
    for (int j=0;j<4;j++){
      int n = n0 + tx*4 + j;
      if (n >= N) continue;
      float v = acc[i][j];
      if (bias) v += bias[n];
      if (leaky) v = v > 0.f ? v : 0.1f*v;
      C[(long)m*N + n] = v;
    }
  }
}

// ---------- device-scope grid barrier (generation counter) ----------
DEV void gridbar(unsigned* cnt, unsigned* gen, unsigned nblk){
  __syncthreads();                       // all waves drain stores (vmcnt 0 at s_barrier)
  if (threadIdx.x == 0){
    __threadfence();                     // agent release: make h-stores visible
    unsigned g = __hip_atomic_load(gen, __ATOMIC_ACQUIRE, __HIP_MEMORY_SCOPE_AGENT);
    unsigned a = __hip_atomic_fetch_add(cnt, 1u, __ATOMIC_ACQ_REL, __HIP_MEMORY_SCOPE_AGENT);
    if (a == nblk - 1u){
      __hip_atomic_store(cnt, 0u, __ATOMIC_RELAXED, __HIP_MEMORY_SCOPE_AGENT);
      __hip_atomic_fetch_add(gen, 1u, __ATOMIC_ACQ_REL, __HIP_MEMORY_SCOPE_AGENT);
    } else {
      while (__hip_atomic_load(gen, __ATOMIC_RELAXED, __HIP_MEMORY_SCOPE_AGENT) == g){
        __builtin_amdgcn_s_sleep(1);
      }
    }
    __threadfence();                     // agent acquire: invalidate stale caches
  }
  __syncthreads();
}

// ---------- weight-stationary grid-synced LSTM (one layer, 96 steps) ----------
// 100 blocks = 2 dirs x 50 slices (8 jj each). Block keeps its 32 weight rows
// (4 gates x 8 jj x 400) in LDS for the whole layer; 16 batches amortize them.
// G: [bat][t][3200] = x@Wih^T + bias. hbufG: [parity][dir][bat][400].
// xout: [bat][t][800] (fwd|bwd).
__global__ __launch_bounds__(128) void lstm_grid(const float* __restrict__ G,
                                                 const float* __restrict__ whh,
                                                 float* __restrict__ xout,
                                                 float* __restrict__ hbufG,
                                                 unsigned* __restrict__ bar,
                                                 int layer){
  __shared__ float Wl[32*404];    // 32 rows x 400 (+4 pad) = 51.7KB
  __shared__ float hl[16*404];    // 16 bat x 400 (+4 pad)  = 25.9KB
  __shared__ float gb[32][17];    // gate dots [row][bat]
  int tid = threadIdx.x;
  int bid = blockIdx.x;
  int dir = bid / 50;
  int slice = bid % 50;
  int jj0 = slice * 8;
  // load weight slice: local row r: g=r>>3, jjr=r&7 -> global row g*400+jj0+jjr
  const float* whhL = whh + (size_t)(layer*2 + dir)*1600*400;
  for (int i = tid; i < 3200; i += 128){        // 32 rows * 100 float4
    int r = i/100, k4 = i%100;
    int g = r>>3, jjr = r&7;
    float4 v = *(const float4*)(whhL + (size_t)(g*400 + jj0 + jjr)*400 + k4*4);
    *(float4*)&Wl[r*404 + k4*4] = v;
  }
  for (int i = tid; i < 16*404; i += 128) hl[i] = 0.f;
  // roles
  int ks   = (tid>>4)&3;                        // k-chunk 0..3 (100 k each)
  int tile = (tid & 15) | ((tid>>6)<<4);        // 0..31
  int batg = tile & 3, rowg = tile >> 2;        // 4 bats x 4 rows per tile
  int ebat = tid >> 3, ejj = tid & 7;           // epilogue: one (bat,jj) per thread
  const float* hb = hl + batg*4*404;
  const float* wb = Wl + rowg*4*404;
  const float* gbase = G + (size_t)ebat*96*3200 + dir*1600 + jj0 + ejj;
  float* xo = xout + (size_t)ebat*96*800 + dir*400 + jj0 + ejj;
  float c = 0.f;
  __syncthreads();
  for (int s = 0; s < 96; s++){
    int t = dir ? 95 - s : s;
    // prefetch G gates for epilogue (independent of h)
    const float* gp = gbase + (size_t)t*3200;
    float g0 = gp[0], g1 = gp[400], g2 = gp[800], g3 = gp[1200];
    // dot phase: 4x4 tile over own k-chunk
    float acc[4][4] = {};
    int kend = ks*25 + 25;
    #pragma unroll 5
    for (int k4 = ks*25; k4 < kend; ++k4){
      float4 h0 = *(const float4*)&hb[0*404 + k4*4];
      float4 h1 = *(const float4*)&hb[1*404 + k4*4];
      float4 h2 = *(const float4*)&hb[2*404 + k4*4];
      float4 h3 = *(const float4*)&hb[3*404 + k4*4];
      float4 w0 = *(const float4*)&wb[0*404 + k4*4];
      float4 w1 = *(const float4*)&wb[1*404 + k4*4];
      float4 w2 = *(const float4*)&wb[2*404 + k4*4];
      float4 w3 = *(const float4*)&wb[3*404 + k4*4];
      #pragma unroll
      for (int bi=0; bi<4; bi++){
        float4 hq = bi==0?h0: bi==1?h1: bi==2?h2: h3;
        #pragma unroll
        for (int ri=0; ri<4; ri++){
          float4 wq = ri==0?w0: ri==1?w1: ri==2?w2: w3;
          acc[bi][ri] = fmaf(hq.x,wq.x, fmaf(hq.y,wq.y,
                        fmaf(hq.z,wq.z, fmaf(hq.w,wq.w, acc[bi][ri]))));
        }
      }
    }
    // k-split reduce (ks encoded in lane bits 4,5)
    #pragma unroll
    for (int bi=0; bi<4; bi++)
      #pragma unroll
      for (int ri=0; ri<4; ri++){
        float v = acc[bi][ri];
        v += __shfl_xor(v, 16);
        v += __shfl_xor(v, 32);
        acc[bi][ri] = v;
      }
    if (ks == 0){
      #pragma unroll
      for (int ri=0; ri<4; ri++)
        #pragma unroll
        for (int bi=0; bi<4; bi++)
          gb[rowg*4+ri][batg*4+bi] = acc[bi][ri];
    }
    __syncthreads();
    // epilogue: gates -> c,h   (local row = g*8 + jj)
    float ai = gb[     ejj][ebat] + g0;
    float af = gb[ 8 + ejj][ebat] + g1;
    float ag = gb[16 + ejj][ebat] + g2;
    float ao = gb[24 + ejj][ebat] + g3;
    c = sigf(af)*c + sigf(ai)*tanhf(ag);
    float hv = sigf(ao)*tanhf(c);
    int par = s & 1;
    hbufG[((size_t)(par*2 + dir)*16 + ebat)*400 + jj0 + ejj] = hv;
    xo[(size_t)t*800] = hv;
    if (s < 95){
      gridbar(bar, bar+1, NBLK_LSTM);
      // reload full h for own dir
      const float4* hsrc = (const float4*)(hbufG + (size_t)(par*2 + dir)*16*400);
      for (int i = tid; i < 1600; i += 128){
        int bb = i/100, k4 = i%100;
        *(float4*)&hl[bb*404 + k4*4] = hsrc[i];
      }
      __syncthreads();
    }
  }
}

// ---------- log_softmax over last axis of s_arc, write transposed p ----------
__global__ __launch_bounds__(256) void softmax_p(const float* __restrict__ sarc,
                                                 float* __restrict__ p){
  int row  = blockIdx.x*4 + (threadIdx.x >> 6);  // 0..1535  (b,x)
  int lane = threadIdx.x & 63;
  int b = row/96, x = row%96;
  const float* s = sarc + (long)(b*96 + x)*96;
  float v1 = s[lane];
  float v2 = (lane+64 < 96) ? s[lane+64] : -INFINITY;
  float mx = wred_max(fmaxf(v1,v2));
  float sm = wred_sum(__expf(v1-mx) + __expf(v2-mx));
  float lse = mx + __logf(sm);
  float* pr = p + (long)b*9216;
  pr[lane*96 + x] = v1 - lse;
  if (lane+64 < 96) pr[(lane+64)*96 + x] = v2 - lse;
}

// ---------- best_score ----------
__global__ __launch_bounds__(128) void best_kern(const float* __restrict__ p,
                                                 const float* __restrict__ multinomial,
                                                 const int* __restrict__ labels,
                                                 const int* __restrict__ heads,
                                                 float* __restrict__ best){
  int b = blockIdx.x, tid = threadIdx.x;
  float acc = 0.f;
  for (int ti = tid; ti < 95; ti += 128) {
    int y = heads[b*95 + ti];
    int x = ti + 1;
    acc += p[(long)b*9216 + y*96 + x]
         + multinomial[(long)labels[b*96 + y]*64 + labels[b*96 + x]];
  }
  acc = wred_sum(acc);
  __shared__ float tmp[2];
  if ((tid & 63) == 0) tmp[tid >> 6] = acc;
  __syncthreads();
  if (tid == 0) best[b] = tmp[0] + tmp[1];
}

// ---------- Eisner inside algorithm, one block per batch element ----------
__global__ __launch_bounds__(1024) void inside_kern(const float* __restrict__ p,
                                                    float* __restrict__ part){
  __shared__ float Cp[96][97];
  __shared__ float Ipp[96][97];
  int b = blockIdx.x;
  const float* pB = p + (long)b*9216;
  int tid = threadIdx.x;
  for (int idx = tid; idx < 96*97; idx += 1024) {
    int row = idx/97, col = idx%97;
    Cp[row][col] = (row == col) ? 0.f : -1e9f;
    Ipp[row][col] = -1e9f;
  }
  __syncthreads();
  int wave = tid >> 6, lane = tid & 63;
  for (int w = 1; w < 96; w++) {
    for (int i = wave; i < 96 - w; i += 16) {
      int j = i + w;
      float v1 = -INFINITY, v2 = -INFINITY;
      if (lane < w)    v1 = Cp[i][i+lane]    + Cp[j][i+1+lane];
      if (lane+64 < w) v2 = Cp[i][i+64+lane] + Cp[j][i+65+lane];
      float mx = wred_max(fmaxf(v1,v2));
      float sm = wred_sum(__expf(v1-mx) + __expf(v2-mx));
      float inc = mx + __logf(sm);
      float ir = inc + pB[i*96 + j];
      float il = inc + pB[j*96 + i];
      int rr1 = lane+1, rr2 = lane+65;
      v1 = (rr1 < w) ? Ipp[i][i+rr1] + Cp[i+rr1][j] : (rr1 == w ? ir : -INFINITY);
      v2 = (rr2 < w) ? Ipp[i][i+rr2] + Cp[i+rr2][j] : (rr2 == w ? ir : -INFINITY);
      mx = wred_max(fmaxf(v1,v2));
      sm = wred_sum(__expf(v1-mx) + __expf(v2-mx));
      float cr = mx + __logf(sm);
      int r1 = lane, r2 = lane+64;
      v1 = (r1 == 0) ? il : ((r1 < w) ? Cp[i+r1][i] + Ipp[j][i+r1] : -INFINITY);
      v2 = (r2 < w) ? Cp[i+r2][i] + Ipp[j][i+r2] : -INFINITY;
      mx = wred_max(fmaxf(v1,v2));
      sm = wred_sum(__expf(v1-mx) + __expf(v2-mx));
      float cl = mx + __logf(sm);
      if (lane == 0) {
        Ipp[i][j] = ir; Ipp[j][i] = il;
        Cp[i][j] = cr;  Cp[j][i] = cl;
      }
    }
    __syncthreads();
  }
  if (tid == 0) part[b] = Cp[0][95];
}

// ---------- final mean ----------
__global__ __launch_bounds__(64) void final_kern(const float* __restrict__ part,
                                                 const float* __restrict__ best,
                                                 float* __restrict__ out){
  int lane = threadIdx.x;
  float v = (lane < 16) ? part[lane] - best[lane] : 0.f;
  v = wred_sum(v);
  if (lane == 0) out[0] = v * (1.f/16.f);
}

extern "C" void kernel_launch(void* const* d_in, const int* in_sizes, int n_in,
                              void* d_out, int out_size, void* d_ws, size_t ws_size,
                              hipStream_t stream) {
  const float* emb   = (const float*)d_in[0];
  const float* multi = (const float*)d_in[1];
  const float* wih0  = (const float*)d_in[2];
  const float* wih   = (const float*)d_in[3];
  const float* whh   = (const float*)d_in[4];
  const float* bias  = (const float*)d_in[5];
  const float* mhw   = (const float*)d_in[6];
  const float* mhb   = (const float*)d_in[7];
  const float* mdw   = (const float*)d_in[8];
  const float* mdb   = (const float*)d_in[9];
  const float* biaf  = (const float*)d_in[10];
  const int*   labels= (const int*)d_in[11];
  const int*   heads = (const int*)d_in[12];
  float* out = (float*)d_out;

  float* ws = (float*)d_ws;
  size_t off = 0;
  auto alloc = [&](size_t n){ float* q = ws + off; off += n; return q; };
  float* G    = alloc(1536L*3200);
  float* x0   = alloc(1536L*768);
  float* xA   = alloc(1536L*800);
  float* xB   = alloc(1536L*800);
  float* WTb  = alloc(500L*500);
  float* arcH = alloc(1536L*500);
  float* arcD = alloc(1536L*500);
  float* tmp  = alloc(1536L*500);
  float* sarc = alloc(16L*96*96);
  float* pbuf = alloc(16L*96*96);
  float* hbufG= alloc(2L*2*16*400);
  unsigned* bar = (unsigned*)alloc(16);
  float* part = alloc(16);
  float* best = alloc(16);
  (void)ws_size; (void)in_sizes; (void)n_in; (void)out_size;

  hipMemsetAsync(bar, 0, 64, stream);   // barrier cnt/gen must start at 0

  embed_kern<<<(1536*768)/256, 256, 0, stream>>>(emb, labels, x0);
  trans_sq<<<(250000+255)/256, 256, 0, stream>>>(biaf, WTb);

  const float* xin = x0;
  float* xout = xA;
  for (int l = 0; l < 3; l++) {
    int Kd = (l==0) ? 768 : 800;
    const float* W = (l==0) ? wih0 : wih + (size_t)(l-1)*2*1600*800;
    dim3 gp(24, 50, 1);
    gemm_abt<<<gp, 256, 0, stream>>>(xin, W, G, bias + l*3200, 1536, 3200, Kd, 0,0,0, 0);
    lstm_grid<<<NBLK_LSTM, 128, 0, stream>>>(G, whh, xout, hbufG, bar, l);
    xin = xout;
    xout = (l==0) ? xB : xA;
  }
  // xin == xA (l0:x0->xA, l1:xA->xB, l2:xB->xA)
  dim3 gm(24, 8, 1);
  gemm_abt<<<gm, 256, 0, stream>>>(xin,  mhw, arcH, mhb, 1536, 500, 800, 0,0,0, 1);
  gemm_abt<<<gm, 256, 0, stream>>>(xin,  mdw, arcD, mdb, 1536, 500, 800, 0,0,0, 1);
  gemm_abt<<<gm, 256, 0, stream>>>(arcD, WTb, tmp, nullptr, 1536, 500, 500, 0,0,0, 0);
  dim3 gs(2, 2, 16);
  gemm_abt<<<gs, 256, 0, stream>>>(tmp, arcH, sarc, nullptr, 96, 96, 500,
                                   96L*500, 96L*500, 96L*96, 0);
  softmax_p<<<384, 256, 0, stream>>>(sarc, pbuf);
  best_kern<<<16, 128, 0, stream>>>(pbuf, multi, labels, heads, best);
  inside_kern<<<16, 1024, 0, stream>>>(pbuf, part);
  final_kern<<<1, 64, 0, stream>>>(part, best, out);
}

// Round 5
// 6022.815 us; speedup vs baseline: 1.6002x; 1.0139x over previous
//
#include <hip/hip_runtime.h>
#include <cmath>

#define DEV __device__ __forceinline__

// ---------- constants ----------
// B=16, T=96, K=64, D=768, H=400, L=3, M=500
// BT = 1536, 4H = 1600, both dirs = 3200, 2H = 800
// NOTE: the LSTM stack is chaotic (||Whh||~6): everything feeding the
// recurrence must be fp32-exact. fp16 weights failed with absmax 1355 (r2).
// NOTE r4: single-cacheline counter grid-barrier = ~14us/step (100 serialized
// cross-XCD RMWs). Distributed per-block flags instead.

#define NBLK_LSTM 100

DEV float wred_max(float v){ for(int o=32;o;o>>=1) v=fmaxf(v,__shfl_xor(v,o)); return v; }
DEV float wred_sum(float v){ for(int o=32;o;o>>=1) v+=__shfl_xor(v,o); return v; }
DEV float sigf(float x){ return 1.f/(1.f+__expf(-x)); }

// ---------- embedding gather ----------
__global__ __launch_bounds__(256) void embed_kern(const float* __restrict__ tab,
                                                  const int* __restrict__ labels,
                                                  float* __restrict__ x0){
  long idx = (long)blockIdx.x*256 + threadIdx.x;   // BT*768
  if (idx >= 1536L*768) return;
  int m = (int)(idx/768), d = (int)(idx%768);
  x0[idx] = tab[(long)labels[m]*768 + d];
}

// ---------- transpose biaffine 500x500 ----------
__global__ __launch_bounds__(256) void trans_sq(const float* __restrict__ w,
                                                float* __restrict__ wt){
  int idx = blockIdx.x*256 + threadIdx.x;          // 250,000
  if (idx >= 250000) return;
  int j = idx/500, i = idx%500;
  wt[idx] = w[(long)i*500 + j];                    // wt[j][i] = w[i][j]
}

// ---------- generic fp32 GEMM: C[m,n] = sum_k A[m,k]*B[n,k] (+bias, leaky) ----------
__global__ __launch_bounds__(256) void gemm_abt(const float* __restrict__ A,
                                                const float* __restrict__ Bm,
                                                float* __restrict__ C,
                                                const float* __restrict__ bias,
                                                int M, int N, int K,
                                                long sA, long sB, long sC, int leaky){
  A  += (long)blockIdx.z * sA;
  Bm += (long)blockIdx.z * sB;
  C  += (long)blockIdx.z * sC;
  __shared__ float As[16][68];
  __shared__ float Bs[16][68];
  int tid = threadIdx.x;
  int tx = tid & 15, ty = tid >> 4;
  int m0 = blockIdx.x * 64, n0 = blockIdx.y * 64;
  int lrow = tid >> 2, lc = (tid & 3) * 4;
  float acc[4][4] = {};
  for (int k0 = 0; k0 < K; k0 += 16) {
    #pragma unroll
    for (int u = 0; u < 4; u++) {
      int k = k0 + lc + u;
      int am = m0 + lrow;
      As[lc+u][lrow] = (am < M && k < K) ? A[(long)am*K + k] : 0.f;
      int bn = n0 + lrow;
      Bs[lc+u][lrow] = (bn < N && k < K) ? Bm[(long)bn*K + k] : 0.f;
    }
    __syncthreads();
    #pragma unroll
    for (int kk = 0; kk < 16; kk++) {
      float a[4], bb[4];
      #pragma unroll
      for (int u=0;u<4;u++){ a[u]=As[kk][ty*4+u]; bb[u]=Bs[kk][tx*4+u]; }
      #pragma unroll
      for (int i=0;i<4;i++)
        #pragma unroll
        for (int j=0;j<4;j++) acc[i][j] = fmaf(a[i], bb[j], acc[i][j]);
    }
    __syncthreads();
  }
  #pragma unroll
  for (int i=0;i<4;i++){
    int m = m0 + ty*4 + i;
    if (m >= M) continue;
    #pragma unroll
    for (int j=0;j<4;j++){
      int n = n0 + tx*4 + j;
      if (n >= N) continue;
      float v = acc[i][j];
      if (bias) v += bias[n];
      if (leaky) v = v > 0.f ? v : 0.1f*v;
      C[(long)m*N + n] = v;
    }
  }
}

// ---------- weight-stationary grid-synced LSTM (one layer, 96 steps) ----------
// 100 blocks = 2 dirs x 50 slices (8 jj each). Block keeps its 32 weight rows
// (4 gates x 8 jj x 400) in LDS for the whole layer; 16 batches amortize them.
// Sync: distributed flags — one 64B line per block, single writer, monotonic
// value layer*95+s+1. Publish: threadfence + release store. Wait: thread tid
// polls flag[tid] relaxed, then acquire fence. (r4 counter barrier was 14us.)
// G: [bat][t][3200] = x@Wih^T + bias. hbufG: [parity][dir][bat][400].
// xout: [bat][t][800] (fwd|bwd).
__global__ __launch_bounds__(128) void lstm_grid(const float* __restrict__ G,
                                                 const float* __restrict__ whh,
                                                 float* __restrict__ xout,
                                                 float* __restrict__ hbufG,
                                                 unsigned* __restrict__ flags,
                                                 int layer){
  __shared__ float Wl[32*404];    // 32 rows x 400 (+4 pad) = 51.7KB
  __shared__ float hl[16*404];    // 16 bat x 400 (+4 pad)  = 25.9KB
  __shared__ float gb[32][17];    // gate dots [row][bat]
  int tid = threadIdx.x;
  int bid = blockIdx.x;
  int dir = bid / 50;
  int slice = bid % 50;
  int jj0 = slice * 8;
  // load weight slice: local row r: g=r>>3, jjr=r&7 -> global row g*400+jj0+jjr
  const float* whhL = whh + (size_t)(layer*2 + dir)*1600*400;
  for (int i = tid; i < 3200; i += 128){        // 32 rows * 100 float4
    int r = i/100, k4 = i%100;
    int g = r>>3, jjr = r&7;
    float4 v = *(const float4*)(whhL + (size_t)(g*400 + jj0 + jjr)*400 + k4*4);
    *(float4*)&Wl[r*404 + k4*4] = v;
  }
  for (int i = tid; i < 16*404; i += 128) hl[i] = 0.f;
  // roles
  int ks   = (tid>>4)&3;                        // k-chunk 0..3 (100 k each)
  int tile = (tid & 15) | ((tid>>6)<<4);        // 0..31
  int batg = tile & 3, rowg = tile >> 2;        // 4 bats x 4 rows per tile
  int ebat = tid >> 3, ejj = tid & 7;           // epilogue: one (bat,jj) per thread
  const float* hb = hl + batg*4*404;
  const float* wb = Wl + rowg*4*404;
  const float* gbase = G + (size_t)ebat*96*3200 + dir*1600 + jj0 + ejj;
  float* xo = xout + (size_t)ebat*96*800 + dir*400 + jj0 + ejj;
  float c = 0.f;
  // G gates for s=0
  {
    const float* gp = gbase + (size_t)(dir ? 95 : 0)*3200;
    // loaded below into g0..g3
  }
  int t0 = dir ? 95 : 0;
  const float* gp0 = gbase + (size_t)t0*3200;
  float g0 = gp0[0], g1 = gp0[400], g2 = gp0[800], g3 = gp0[1200];
  __syncthreads();
  for (int s = 0; s < 96; s++){
    int t = dir ? 95 - s : s;
    // dot phase: 4x4 tile over own k-chunk
    float acc[4][4] = {};
    int kend = ks*25 + 25;
    #pragma unroll 5
    for (int k4 = ks*25; k4 < kend; ++k4){
      float4 h0 = *(const float4*)&hb[0*404 + k4*4];
      float4 h1 = *(const float4*)&hb[1*404 + k4*4];
      float4 h2 = *(const float4*)&hb[2*404 + k4*4];
      float4 h3 = *(const float4*)&hb[3*404 + k4*4];
      float4 w0 = *(const float4*)&wb[0*404 + k4*4];
      float4 w1 = *(const float4*)&wb[1*404 + k4*4];
      float4 w2 = *(const float4*)&wb[2*404 + k4*4];
      float4 w3 = *(const float4*)&wb[3*404 + k4*4];
      #pragma unroll
      for (int bi=0; bi<4; bi++){
        float4 hq = bi==0?h0: bi==1?h1: bi==2?h2: h3;
        #pragma unroll
        for (int ri=0; ri<4; ri++){
          float4 wq = ri==0?w0: ri==1?w1: ri==2?w2: w3;
          acc[bi][ri] = fmaf(hq.x,wq.x, fmaf(hq.y,wq.y,
                        fmaf(hq.z,wq.z, fmaf(hq.w,wq.w, acc[bi][ri]))));
        }
      }
    }
    // k-split reduce (ks encoded in lane bits 4,5)
    #pragma unroll
    for (int bi=0; bi<4; bi++)
      #pragma unroll
      for (int ri=0; ri<4; ri++){
        float v = acc[bi][ri];
        v += __shfl_xor(v, 16);
        v += __shfl_xor(v, 32);
        acc[bi][ri] = v;
      }
    if (ks == 0){
      #pragma unroll
      for (int ri=0; ri<4; ri++)
        #pragma unroll
        for (int bi=0; bi<4; bi++)
          gb[rowg*4+ri][batg*4+bi] = acc[bi][ri];
    }
    __syncthreads();
    // epilogue: gates -> c,h   (local row = g*8 + jj)
    float ai = gb[     ejj][ebat] + g0;
    float af = gb[ 8 + ejj][ebat] + g1;
    float ag = gb[16 + ejj][ebat] + g2;
    float ao = gb[24 + ejj][ebat] + g3;
    c = sigf(af)*c + sigf(ai)*tanhf(ag);
    float hv = sigf(ao)*tanhf(c);
    int par = s & 1;
    hbufG[((size_t)(par*2 + dir)*16 + ebat)*400 + jj0 + ejj] = hv;
    xo[(size_t)t*800] = hv;
    if (s < 95){
      unsigned target = (unsigned)(layer*95 + s + 1);
      __syncthreads();                       // drain all h stores (vmcnt 0)
      if (tid == 0){
        __threadfence();                     // release: flush h to coherence point
        __hip_atomic_store(&flags[bid*16], target, __ATOMIC_RELEASE,
                           __HIP_MEMORY_SCOPE_AGENT);
      }
      // prefetch next-step G gates under the spin
      int tn = dir ? 95 - (s+1) : (s+1);
      const float* gp = gbase + (size_t)tn*3200;
      g0 = gp[0]; g1 = gp[400]; g2 = gp[800]; g3 = gp[1200];
      if (tid < NBLK_LSTM){
        while (__hip_atomic_load(&flags[tid*16], __ATOMIC_RELAXED,
                                 __HIP_MEMORY_SCOPE_AGENT) < target){
          __builtin_amdgcn_s_sleep(1);
        }
      }
      __syncthreads();
      if (tid == 0) __threadfence();         // acquire: invalidate stale caches
      __syncthreads();
      // reload full h for own dir
      const float4* hsrc = (const float4*)(hbufG + (size_t)(par*2 + dir)*16*400);
      for (int i = tid; i < 1600; i += 128){
        int bb = i/100, k4 = i%100;
        *(float4*)&hl[bb*404 + k4*4] = hsrc[i];
      }
      __syncthreads();
    }
  }
}

// ---------- log_softmax over last axis of s_arc, write transposed p ----------
__global__ __launch_bounds__(256) void softmax_p(const float* __restrict__ sarc,
                                                 float* __restrict__ p){
  int row  = blockIdx.x*4 + (threadIdx.x >> 6);  // 0..1535  (b,x)
  int lane = threadIdx.x & 63;
  int b = row/96, x = row%96;
  const float* s = sarc + (long)(b*96 + x)*96;
  float v1 = s[lane];
  float v2 = (lane+64 < 96) ? s[lane+64] : -INFINITY;
  float mx = wred_max(fmaxf(v1,v2));
  float sm = wred_sum(__expf(v1-mx) + __expf(v2-mx));
  float lse = mx + __logf(sm);
  float* pr = p + (long)b*9216;
  pr[lane*96 + x] = v1 - lse;
  if (lane+64 < 96) pr[(lane+64)*96 + x] = v2 - lse;
}

// ---------- best_score ----------
__global__ __launch_bounds__(128) void best_kern(const float* __restrict__ p,
                                                 const float* __restrict__ multinomial,
                                                 const int* __restrict__ labels,
                                                 const int* __restrict__ heads,
                                                 float* __restrict__ best){
  int b = blockIdx.x, tid = threadIdx.x;
  float acc = 0.f;
  for (int ti = tid; ti < 95; ti += 128) {
    int y = heads[b*95 + ti];
    int x = ti + 1;
    acc += p[(long)b*9216 + y*96 + x]
         + multinomial[(long)labels[b*96 + y]*64 + labels[b*96 + x]];
  }
  acc = wred_sum(acc);
  __shared__ float tmp[2];
  if ((tid & 63) == 0) tmp[tid >> 6] = acc;
  __syncthreads();
  if (tid == 0) best[b] = tmp[0] + tmp[1];
}

// ---------- Eisner inside algorithm, one block per batch element ----------
__global__ __launch_bounds__(1024) void inside_kern(const float* __restrict__ p,
                                                    float* __restrict__ part){
  __shared__ float Cp[96][97];
  __shared__ float Ipp[96][97];
  int b = blockIdx.x;
  const float* pB = p + (long)b*9216;
  int tid = threadIdx.x;
  for (int idx = tid; idx < 96*97; idx += 1024) {
    int row = idx/97, col = idx%97;
    Cp[row][col] = (row == col) ? 0.f : -1e9f;
    Ipp[row][col] = -1e9f;
  }
  __syncthreads();
  int wave = tid >> 6, lane = tid & 63;
  for (int w = 1; w < 96; w++) {
    for (int i = wave; i < 96 - w; i += 16) {
      int j = i + w;
      float v1 = -INFINITY, v2 = -INFINITY;
      if (lane < w)    v1 = Cp[i][i+lane]    + Cp[j][i+1+lane];
      if (lane+64 < w) v2 = Cp[i][i+64+lane] + Cp[j][i+65+lane];
      float mx = wred_max(fmaxf(v1,v2));
      float sm = wred_sum(__expf(v1-mx) + __expf(v2-mx));
      float inc = mx + __logf(sm);
      float ir = inc + pB[i*96 + j];
      float il = inc + pB[j*96 + i];
      int rr1 = lane+1, rr2 = lane+65;
      v1 = (rr1 < w) ? Ipp[i][i+rr1] + Cp[i+rr1][j] : (rr1 == w ? ir : -INFINITY);
      v2 = (rr2 < w) ? Ipp[i][i+rr2] + Cp[i+rr2][j] : (rr2 == w ? ir : -INFINITY);
      mx = wred_max(fmaxf(v1,v2));
      sm = wred_sum(__expf(v1-mx) + __expf(v2-mx));
      float cr = mx + __logf(sm);
      int r1 = lane, r2 = lane+64;
      v1 = (r1 == 0) ? il : ((r1 < w) ? Cp[i+r1][i] + Ipp[j][i+r1] : -INFINITY);
      v2 = (r2 < w) ? Cp[i+r2][i] + Ipp[j][i+r2] : -INFINITY;
      mx = wred_max(fmaxf(v1,v2));
      sm = wred_sum(__expf(v1-mx) + __expf(v2-mx));
      float cl = mx + __logf(sm);
      if (lane == 0) {
        Ipp[i][j] = ir; Ipp[j][i] = il;
        Cp[i][j] = cr;  Cp[j][i] = cl;
      }
    }
    __syncthreads();
  }
  if (tid == 0) part[b] = Cp[0][95];
}

// ---------- final mean ----------
__global__ __launch_bounds__(64) void final_kern(const float* __restrict__ part,
                                                 const float* __restrict__ best,
                                                 float* __restrict__ out){
  int lane = threadIdx.x;
  float v = (lane < 16) ? part[lane] - best[lane] : 0.f;
  v = wred_sum(v);
  if (lane == 0) out[0] = v * (1.f/16.f);
}

extern "C" void kernel_launch(void* const* d_in, const int* in_sizes, int n_in,
                              void* d_out, int out_size, void* d_ws, size_t ws_size,
                              hipStream_t stream) {
  const float* emb   = (const float*)d_in[0];
  const float* multi = (const float*)d_in[1];
  const float* wih0  = (const float*)d_in[2];
  const float* wih   = (const float*)d_in[3];
  const float* whh   = (const float*)d_in[4];
  const float* bias  = (const float*)d_in[5];
  const float* mhw   = (const float*)d_in[6];
  const float* mhb   = (const float*)d_in[7];
  const float* mdw   = (const float*)d_in[8];
  const float* mdb   = (const float*)d_in[9];
  const float* biaf  = (const float*)d_in[10];
  const int*   labels= (const int*)d_in[11];
  const int*   heads = (const int*)d_in[12];
  float* out = (float*)d_out;

  float* ws = (float*)d_ws;
  size_t off = 0;
  auto alloc = [&](size_t n){ float* q = ws + off; off += n; return q; };
  float* G    = alloc(1536L*3200);
  float* x0   = alloc(1536L*768);
  float* xA   = alloc(1536L*800);
  float* xB   = alloc(1536L*800);
  float* WTb  = alloc(500L*500);
  float* arcH = alloc(1536L*500);
  float* arcD = alloc(1536L*500);
  float* tmp  = alloc(1536L*500);
  float* sarc = alloc(16L*96*96);
  float* pbuf = alloc(16L*96*96);
  float* hbufG= alloc(2L*2*16*400);
  unsigned* flags = (unsigned*)alloc(NBLK_LSTM*16);
  float* part = alloc(16);
  float* best = alloc(16);
  (void)ws_size; (void)in_sizes; (void)n_in; (void)out_size;

  hipMemsetAsync(flags, 0, NBLK_LSTM*16*sizeof(unsigned), stream);

  embed_kern<<<(1536*768)/256, 256, 0, stream>>>(emb, labels, x0);
  trans_sq<<<(250000+255)/256, 256, 0, stream>>>(biaf, WTb);

  const float* xin = x0;
  float* xout = xA;
  for (int l = 0; l < 3; l++) {
    int Kd = (l==0) ? 768 : 800;
    const float* W = (l==0) ? wih0 : wih + (size_t)(l-1)*2*1600*800;
    dim3 gp(24, 50, 1);
    gemm_abt<<<gp, 256, 0, stream>>>(xin, W, G, bias + l*3200, 1536, 3200, Kd, 0,0,0, 0);
    lstm_grid<<<NBLK_LSTM, 128, 0, stream>>>(G, whh, xout, hbufG, flags, l);
    xin = xout;
    xout = (l==0) ? xB : xA;
  }
  // xin == xA (l0:x0->xA, l1:xA->xB, l2:xB->xA)
  dim3 gm(24, 8, 1);
  gemm_abt<<<gm, 256, 0, stream>>>(xin,  mhw, arcH, mhb, 1536, 500, 800, 0,0,0, 1);
  gemm_abt<<<gm, 256, 0, stream>>>(xin,  mdw, arcD, mdb, 1536, 500, 800, 0,0,0, 1);
  gemm_abt<<<gm, 256, 0, stream>>>(arcD, WTb, tmp, nullptr, 1536, 500, 500, 0,0,0, 0);
  dim3 gs(2, 2, 16);
  gemm_abt<<<gs, 256, 0, stream>>>(tmp, arcH, sarc, nullptr, 96, 96, 500,
                                   96L*500, 96L*500, 96L*96, 0);
  softmax_p<<<384, 256, 0, stream>>>(sarc, pbuf);
  best_kern<<<16, 128, 0, stream>>>(pbuf, multi, labels, heads, best);
  inside_kern<<<16, 1024, 0, stream>>>(pbuf, part);
  final_kern<<<1, 64, 0, stream>>>(part, best, out);
}

// Round 6
// 3174.273 us; speedup vs baseline: 3.0362x; 1.8974x over previous
//
#include <hip/hip_runtime.h>
#include <cmath>

#define DEV __device__ __forceinline__

// ---------- constants ----------
// B=16, T=96, K=64, D=768, H=400, L=3, M=500
// BT = 1536, 4H = 1600, both dirs = 3200, 2H = 800
// NOTE: the LSTM stack is chaotic (||Whh||~6): everything feeding the
// recurrence must be fp32-exact. fp16 weights failed with absmax 1355 (r2).
// NOTE r4: single-cacheline counter grid-barrier = ~14us/step. r5: distributed
// flags + __threadfence = same 14us — the threadfence (buffer_wbl2/buffer_inv
// L2 walks) was the cost, not the RMWs (FETCH 63.5MB = G re-fetched 3x).
// r6: fence-FREE sync — h + flags via cache-bypassing agent-scope atomics;
// __syncthreads() drains vmcnt (stores ack'd at coherent point) before the
// flag store, so no release/acquire cache walks are needed.

#define NBLK_LSTM 100

DEV float wred_max(float v){ for(int o=32;o;o>>=1) v=fmaxf(v,__shfl_xor(v,o)); return v; }
DEV float wred_sum(float v){ for(int o=32;o;o>>=1) v+=__shfl_xor(v,o); return v; }
DEV float sigf(float x){ return 1.f/(1.f+__expf(-x)); }

DEV float agent_ld(const float* p){
  return __hip_atomic_load(p, __ATOMIC_RELAXED, __HIP_MEMORY_SCOPE_AGENT);
}
DEV void agent_st(float* p, float v){
  __hip_atomic_store(p, v, __ATOMIC_RELAXED, __HIP_MEMORY_SCOPE_AGENT);
}

// ---------- embedding gather ----------
__global__ __launch_bounds__(256) void embed_kern(const float* __restrict__ tab,
                                                  const int* __restrict__ labels,
                                                  float* __restrict__ x0){
  long idx = (long)blockIdx.x*256 + threadIdx.x;   // BT*768
  if (idx >= 1536L*768) return;
  int m = (int)(idx/768), d = (int)(idx%768);
  x0[idx] = tab[(long)labels[m]*768 + d];
}

// ---------- transpose biaffine 500x500 ----------
__global__ __launch_bounds__(256) void trans_sq(const float* __restrict__ w,
                                                float* __restrict__ wt){
  int idx = blockIdx.x*256 + threadIdx.x;          // 250,000
  if (idx >= 250000) return;
  int j = idx/500, i = idx%500;
  wt[idx] = w[(long)i*500 + j];                    // wt[j][i] = w[i][j]
}

// ---------- generic fp32 GEMM: C[m,n] = sum_k A[m,k]*B[n,k] (+bias, leaky) ----------
__global__ __launch_bounds__(256) void gemm_abt(const float* __restrict__ A,
                                                const float* __restrict__ Bm,
                                                float* __restrict__ C,
                                                const float* __restrict__ bias,
                                                int M, int N, int K,
                                                long sA, long sB, long sC, int leaky){
  A  += (long)blockIdx.z * sA;
  Bm += (long)blockIdx.z * sB;
  C  += (long)blockIdx.z * sC;
  __shared__ float As[16][68];
  __shared__ float Bs[16][68];
  int tid = threadIdx.x;
  int tx = tid & 15, ty = tid >> 4;
  int m0 = blockIdx.x * 64, n0 = blockIdx.y * 64;
  int lrow = tid >> 2, lc = (tid & 3) * 4;
  float acc[4][4] = {};
  for (int k0 = 0; k0 < K; k0 += 16) {
    #pragma unroll
    for (int u = 0; u < 4; u++) {
      int k = k0 + lc + u;
      int am = m0 + lrow;
      As[lc+u][lrow] = (am < M && k < K) ? A[(long)am*K + k] : 0.f;
      int bn = n0 + lrow;
      Bs[lc+u][lrow] = (bn < N && k < K) ? Bm[(long)bn*K + k] : 0.f;
    }
    __syncthreads();
    #pragma unroll
    for (int kk = 0; kk < 16; kk++) {
      float a[4], bb[4];
      #pragma unroll
      for (int u=0;u<4;u++){ a[u]=As[kk][ty*4+u]; bb[u]=Bs[kk][tx*4+u]; }
      #pragma unroll
      for (int i=0;i<4;i++)
        #pragma unroll
        for (int j=0;j<4;j++) acc[i][j] = fmaf(a[i], bb[j], acc[i][j]);
    }
    __syncthreads();
  }
  #pragma unroll
  for (int i=0;i<4;i++){
    int m = m0 + ty*4 + i;
    if (m >= M) continue;
    #pragma unroll
    for (int j=0;j<4;j++){
      int n = n0 + tx*4 + j;
      if (n >= N) continue;
      float v = acc[i][j];
      if (bias) v += bias[n];
      if (leaky) v = v > 0.f ? v : 0.1f*v;
      C[(long)m*N + n] = v;
    }
  }
}

// ---------- weight-stationary grid-synced LSTM (one layer, 96 steps) ----------
// 100 blocks = 2 dirs x 50 slices (8 jj each). Block keeps its 32 weight rows
// (4 gates x 8 jj x 400) in LDS for the whole layer; 16 batches amortize them.
// Sync (r6): h published via agent-scope relaxed atomic stores (cache-bypass,
// ack'd at the coherent point when vmcnt retires). __syncthreads() drains all
// waves' stores; tid0 then relaxed-stores its flag (monotonic layer*95+s+1,
// one 64B line per block). Readers poll flags relaxed, __syncthreads(), then
// reload h with agent-scope relaxed atomic loads. NO threadfence anywhere.
// G: [bat][t][3200] = x@Wih^T + bias. hbufG: [parity][dir][bat][400].
// xout: [bat][t][800] (fwd|bwd).
__global__ __launch_bounds__(128) void lstm_grid(const float* __restrict__ G,
                                                 const float* __restrict__ whh,
                                                 float* __restrict__ xout,
                                                 float* __restrict__ hbufG,
                                                 unsigned* __restrict__ flags,
                                                 int layer){
  __shared__ float Wl[32*404];    // 32 rows x 400 (+4 pad) = 51.7KB
  __shared__ float hl[16*404];    // 16 bat x 400 (+4 pad)  = 25.9KB
  __shared__ float gb[32][17];    // gate dots [row][bat]
  int tid = threadIdx.x;
  int bid = blockIdx.x;
  int dir = bid / 50;
  int slice = bid % 50;
  int jj0 = slice * 8;
  // load weight slice: local row r: g=r>>3, jjr=r&7 -> global row g*400+jj0+jjr
  const float* whhL = whh + (size_t)(layer*2 + dir)*1600*400;
  for (int i = tid; i < 3200; i += 128){        // 32 rows * 100 float4
    int r = i/100, k4 = i%100;
    int g = r>>3, jjr = r&7;
    float4 v = *(const float4*)(whhL + (size_t)(g*400 + jj0 + jjr)*400 + k4*4);
    *(float4*)&Wl[r*404 + k4*4] = v;
  }
  for (int i = tid; i < 16*404; i += 128) hl[i] = 0.f;
  // roles
  int ks   = (tid>>4)&3;                        // k-chunk 0..3 (100 k each)
  int tile = (tid & 15) | ((tid>>6)<<4);        // 0..31
  int batg = tile & 3, rowg = tile >> 2;        // 4 bats x 4 rows per tile
  int ebat = tid >> 3, ejj = tid & 7;           // epilogue: one (bat,jj) per thread
  const float* hb = hl + batg*4*404;
  const float* wb = Wl + rowg*4*404;
  const float* gbase = G + (size_t)ebat*96*3200 + dir*1600 + jj0 + ejj;
  float* xo = xout + (size_t)ebat*96*800 + dir*400 + jj0 + ejj;
  float c = 0.f;
  int t0 = dir ? 95 : 0;
  const float* gp0 = gbase + (size_t)t0*3200;
  float g0 = gp0[0], g1 = gp0[400], g2 = gp0[800], g3 = gp0[1200];
  __syncthreads();
  for (int s = 0; s < 96; s++){
    int t = dir ? 95 - s : s;
    // dot phase: 4x4 tile over own k-chunk
    float acc[4][4] = {};
    int kend = ks*25 + 25;
    #pragma unroll 5
    for (int k4 = ks*25; k4 < kend; ++k4){
      float4 h0 = *(const float4*)&hb[0*404 + k4*4];
      float4 h1 = *(const float4*)&hb[1*404 + k4*4];
      float4 h2 = *(const float4*)&hb[2*404 + k4*4];
      float4 h3 = *(const float4*)&hb[3*404 + k4*4];
      float4 w0 = *(const float4*)&wb[0*404 + k4*4];
      float4 w1 = *(const float4*)&wb[1*404 + k4*4];
      float4 w2 = *(const float4*)&wb[2*404 + k4*4];
      float4 w3 = *(const float4*)&wb[3*404 + k4*4];
      #pragma unroll
      for (int bi=0; bi<4; bi++){
        float4 hq = bi==0?h0: bi==1?h1: bi==2?h2: h3;
        #pragma unroll
        for (int ri=0; ri<4; ri++){
          float4 wq = ri==0?w0: ri==1?w1: ri==2?w2: w3;
          acc[bi][ri] = fmaf(hq.x,wq.x, fmaf(hq.y,wq.y,
                        fmaf(hq.z,wq.z, fmaf(hq.w,wq.w, acc[bi][ri]))));
        }
      }
    }
    // k-split reduce (ks encoded in lane bits 4,5)
    #pragma unroll
    for (int bi=0; bi<4; bi++)
      #pragma unroll
      for (int ri=0; ri<4; ri++){
        float v = acc[bi][ri];
        v += __shfl_xor(v, 16);
        v += __shfl_xor(v, 32);
        acc[bi][ri] = v;
      }
    if (ks == 0){
      #pragma unroll
      for (int ri=0; ri<4; ri++)
        #pragma unroll
        for (int bi=0; bi<4; bi++)
          gb[rowg*4+ri][batg*4+bi] = acc[bi][ri];
    }
    __syncthreads();
    // epilogue: gates -> c,h   (local row = g*8 + jj)
    float ai = gb[     ejj][ebat] + g0;
    float af = gb[ 8 + ejj][ebat] + g1;
    float ag = gb[16 + ejj][ebat] + g2;
    float ao = gb[24 + ejj][ebat] + g3;
    c = sigf(af)*c + sigf(ai)*tanhf(ag);
    float hv = sigf(ao)*tanhf(c);
    int par = s & 1;
    agent_st(&hbufG[((size_t)(par*2 + dir)*16 + ebat)*400 + jj0 + ejj], hv);
    xo[(size_t)t*800] = hv;
    if (s < 95){
      unsigned target = (unsigned)(layer*95 + s + 1);
      __syncthreads();    // every wave: vmcnt(0) -> h stores ack'd at coherent pt
      if (tid == 0)
        __hip_atomic_store(&flags[bid*16], target, __ATOMIC_RELAXED,
                           __HIP_MEMORY_SCOPE_AGENT);
      // prefetch next-step G gates under the spin (plain loads, L2-cached)
      int tn = dir ? 94 - s : s + 1;
      const float* gp = gbase + (size_t)tn*3200;
      g0 = gp[0]; g1 = gp[400]; g2 = gp[800]; g3 = gp[1200];
      if (tid < NBLK_LSTM){
        while (__hip_atomic_load(&flags[tid*16], __ATOMIC_RELAXED,
                                 __HIP_MEMORY_SCOPE_AGENT) < target){
          __builtin_amdgcn_s_sleep(1);
        }
      }
      __syncthreads();
      // reload full h for own dir (cache-bypassing atomic loads, grouped for ILP)
      const float* hsrc = hbufG + (size_t)(par*2 + dir)*6400;
      float hA[16], hB[16], hC[16], hT0, hT1;
      #pragma unroll
      for (int bat = 0; bat < 16; bat++){
        hA[bat] = agent_ld(hsrc + bat*400 + tid);
        hB[bat] = agent_ld(hsrc + bat*400 + 128 + tid);
        hC[bat] = agent_ld(hsrc + bat*400 + 256 + tid);
      }
      // tail: 16 bats x 16 k (384..399) = 256 elems, 2 per thread
      hT0 = agent_ld(hsrc + (tid>>4)*400 + 384 + (tid&15));
      hT1 = agent_ld(hsrc + ((tid+128)>>4)*400 + 384 + (tid&15));
      #pragma unroll
      for (int bat = 0; bat < 16; bat++){
        hl[bat*404 + tid]       = hA[bat];
        hl[bat*404 + 128 + tid] = hB[bat];
        hl[bat*404 + 256 + tid] = hC[bat];
      }
      hl[(tid>>4)*404 + 384 + (tid&15)] = hT0;
      hl[((tid+128)>>4)*404 + 384 + (tid&15)] = hT1;
      __syncthreads();
    }
  }
}

// ---------- log_softmax over last axis of s_arc, write transposed p ----------
__global__ __launch_bounds__(256) void softmax_p(const float* __restrict__ sarc,
                                                 float* __restrict__ p){
  int row  = blockIdx.x*4 + (threadIdx.x >> 6);  // 0..1535  (b,x)
  int lane = threadIdx.x & 63;
  int b = row/96, x = row%96;
  const float* s = sarc + (long)(b*96 + x)*96;
  float v1 = s[lane];
  float v2 = (lane+64 < 96) ? s[lane+64] : -INFINITY;
  float mx = wred_max(fmaxf(v1,v2));
  float sm = wred_sum(__expf(v1-mx) + __expf(v2-mx));
  float lse = mx + __logf(sm);
  float* pr = p + (long)b*9216;
  pr[lane*96 + x] = v1 - lse;
  if (lane+64 < 96) pr[(lane+64)*96 + x] = v2 - lse;
}

// ---------- best_score ----------
__global__ __launch_bounds__(128) void best_kern(const float* __restrict__ p,
                                                 const float* __restrict__ multinomial,
                                                 const int* __restrict__ labels,
                                                 const int* __restrict__ heads,
                                                 float* __restrict__ best){
  int b = blockIdx.x, tid = threadIdx.x;
  float acc = 0.f;
  for (int ti = tid; ti < 95; ti += 128) {
    int y = heads[b*95 + ti];
    int x = ti + 1;
    acc += p[(long)b*9216 + y*96 + x]
         + multinomial[(long)labels[b*96 + y]*64 + labels[b*96 + x]];
  }
  acc = wred_sum(acc);
  __shared__ float tmp[2];
  if ((tid & 63) == 0) tmp[tid >> 6] = acc;
  __syncthreads();
  if (tid == 0) best[b] = tmp[0] + tmp[1];
}

// ---------- Eisner inside algorithm, one block per batch element ----------
__global__ __launch_bounds__(1024) void inside_kern(const float* __restrict__ p,
                                                    float* __restrict__ part){
  __shared__ float Cp[96][97];
  __shared__ float Ipp[96][97];
  int b = blockIdx.x;
  const float* pB = p + (long)b*9216;
  int tid = threadIdx.x;
  for (int idx = tid; idx < 96*97; idx += 1024) {
    int row = idx/97, col = idx%97;
    Cp[row][col] = (row == col) ? 0.f : -1e9f;
    Ipp[row][col] = -1e9f;
  }
  __syncthreads();
  int wave = tid >> 6, lane = tid & 63;
  for (int w = 1; w < 96; w++) {
    for (int i = wave; i < 96 - w; i += 16) {
      int j = i + w;
      float v1 = -INFINITY, v2 = -INFINITY;
      if (lane < w)    v1 = Cp[i][i+lane]    + Cp[j][i+1+lane];
      if (lane+64 < w) v2 = Cp[i][i+64+lane] + Cp[j][i+65+lane];
      float mx = wred_max(fmaxf(v1,v2));
      float sm = wred_sum(__expf(v1-mx) + __expf(v2-mx));
      float inc = mx + __logf(sm);
      float ir = inc + pB[i*96 + j];
      float il = inc + pB[j*96 + i];
      int rr1 = lane+1, rr2 = lane+65;
      v1 = (rr1 < w) ? Ipp[i][i+rr1] + Cp[i+rr1][j] : (rr1 == w ? ir : -INFINITY);
      v2 = (rr2 < w) ? Ipp[i][i+rr2] + Cp[i+rr2][j] : (rr2 == w ? ir : -INFINITY);
      mx = wred_max(fmaxf(v1,v2));
      sm = wred_sum(__expf(v1-mx) + __expf(v2-mx));
      float cr = mx + __logf(sm);
      int r1 = lane, r2 = lane+64;
      v1 = (r1 == 0) ? il : ((r1 < w) ? Cp[i+r1][i] + Ipp[j][i+r1] : -INFINITY);
      v2 = (r2 < w) ? Cp[i+r2][i] + Ipp[j][i+r2] : -INFINITY;
      mx = wred_max(fmaxf(v1,v2));
      sm = wred_sum(__expf(v1-mx) + __expf(v2-mx));
      float cl = mx + __logf(sm);
      if (lane == 0) {
        Ipp[i][j] = ir; Ipp[j][i] = il;
        Cp[i][j] = cr;  Cp[j][i] = cl;
      }
    }
    __syncthreads();
  }
  if (tid == 0) part[b] = Cp[0][95];
}

// ---------- final mean ----------
__global__ __launch_bounds__(64) void final_kern(const float* __restrict__ part,
                                                 const float* __restrict__ best,
                                                 float* __restrict__ out){
  int lane = threadIdx.x;
  float v = (lane < 16) ? part[lane] - best[lane] : 0.f;
  v = wred_sum(v);
  if (lane == 0) out[0] = v * (1.f/16.f);
}

extern "C" void kernel_launch(void* const* d_in, const int* in_sizes, int n_in,
                              void* d_out, int out_size, void* d_ws, size_t ws_size,
                              hipStream_t stream) {
  const float* emb   = (const float*)d_in[0];
  const float* multi = (const float*)d_in[1];
  const float* wih0  = (const float*)d_in[2];
  const float* wih   = (const float*)d_in[3];
  const float* whh   = (const float*)d_in[4];
  const float* bias  = (const float*)d_in[5];
  const float* mhw   = (const float*)d_in[6];
  const float* mhb   = (const float*)d_in[7];
  const float* mdw   = (const float*)d_in[8];
  const float* mdb   = (const float*)d_in[9];
  const float* biaf  = (const float*)d_in[10];
  const int*   labels= (const int*)d_in[11];
  const int*   heads = (const int*)d_in[12];
  float* out = (float*)d_out;

  float* ws = (float*)d_ws;
  size_t off = 0;
  auto alloc = [&](size_t n){ float* q = ws + off; off += n; return q; };
  float* G    = alloc(1536L*3200);
  float* x0   = alloc(1536L*768);
  float* xA   = alloc(1536L*800);
  float* xB   = alloc(1536L*800);
  float* WTb  = alloc(500L*500);
  float* arcH = alloc(1536L*500);
  float* arcD = alloc(1536L*500);
  float* tmp  = alloc(1536L*500);
  float* sarc = alloc(16L*96*96);
  float* pbuf = alloc(16L*96*96);
  float* hbufG= alloc(2L*2*16*400);
  unsigned* flags = (unsigned*)alloc(NBLK_LSTM*16);
  float* part = alloc(16);
  float* best = alloc(16);
  (void)ws_size; (void)in_sizes; (void)n_in; (void)out_size;

  hipMemsetAsync(flags, 0, NBLK_LSTM*16*sizeof(unsigned), stream);

  embed_kern<<<(1536*768)/256, 256, 0, stream>>>(emb, labels, x0);
  trans_sq<<<(250000+255)/256, 256, 0, stream>>>(biaf, WTb);

  const float* xin = x0;
  float* xout = xA;
  for (int l = 0; l < 3; l++) {
    int Kd = (l==0) ? 768 : 800;
    const float* W = (l==0) ? wih0 : wih + (size_t)(l-1)*2*1600*800;
    dim3 gp(24, 50, 1);
    gemm_abt<<<gp, 256, 0, stream>>>(xin, W, G, bias + l*3200, 1536, 3200, Kd, 0,0,0, 0);
    lstm_grid<<<NBLK_LSTM, 128, 0, stream>>>(G, whh, xout, hbufG, flags, l);
    xin = xout;
    xout = (l==0) ? xB : xA;
  }
  // xin == xA (l0:x0->xA, l1:xA->xB, l2:xB->xA)
  dim3 gm(24, 8, 1);
  gemm_abt<<<gm, 256, 0, stream>>>(xin,  mhw, arcH, mhb, 1536, 500, 800, 0,0,0, 1);
  gemm_abt<<<gm, 256, 0, stream>>>(xin,  mdw, arcD, mdb, 1536, 500, 800, 0,0,0, 1);
  gemm_abt<<<gm, 256, 0, stream>>>(arcD, WTb, tmp, nullptr, 1536, 500, 500, 0,0,0, 0);
  dim3 gs(2, 2, 16);
  gemm_abt<<<gs, 256, 0, stream>>>(tmp, arcH, sarc, nullptr, 96, 96, 500,
                                   96L*500, 96L*500, 96L*96, 0);
  softmax_p<<<384, 256, 0, stream>>>(sarc, pbuf);
  best_kern<<<16, 128, 0, stream>>>(pbuf, multi, labels, heads, best);
  inside_kern<<<16, 1024, 0, stream>>>(pbuf, part);
  final_kern<<<1, 64, 0, stream>>>(part, best, out);
}

// Round 7
// 2846.632 us; speedup vs baseline: 3.3857x; 1.1151x over previous
//
#include <hip/hip_runtime.h>
#include <cmath>

#define DEV __device__ __forceinline__

// ---------- constants ----------
// B=16, T=96, K=64, D=768, H=400, L=3, M=500
// BT = 1536, 4H = 1600, both dirs = 3200, 2H = 800
// NOTE: the LSTM stack is chaotic (||Whh||~6): everything feeding the
// recurrence must be fp32-exact. fp16 weights failed with absmax 1355 (r2).
// NOTE r4: single-cacheline counter grid-barrier = ~14us/step. r5: distributed
// flags + __threadfence = same 14us — the threadfence (buffer_wbl2/buffer_inv
// L2 walks) was the cost, not the RMWs. r6: fence-FREE sync via cache-bypass
// agent-scope atomics = 1490 -> <583 us/layer. KEEP.
// r7: inside_kern task-parallel rewrite (was wave-per-span, 585us: ~24/64
// useful lanes + 12-shfl chains). Now 8-lane groups, 2 phases/width, all
// operands contiguous via third transposed array Xp, p in LDS.

#define NBLK_LSTM 100

DEV float wred_max(float v){ for(int o=32;o;o>>=1) v=fmaxf(v,__shfl_xor(v,o)); return v; }
DEV float wred_sum(float v){ for(int o=32;o;o>>=1) v+=__shfl_xor(v,o); return v; }
DEV float sigf(float x){ return 1.f/(1.f+__expf(-x)); }

DEV float agent_ld(const float* p){
  return __hip_atomic_load(p, __ATOMIC_RELAXED, __HIP_MEMORY_SCOPE_AGENT);
}
DEV void agent_st(float* p, float v){
  __hip_atomic_store(p, v, __ATOMIC_RELAXED, __HIP_MEMORY_SCOPE_AGENT);
}

// ---------- embedding gather ----------
__global__ __launch_bounds__(256) void embed_kern(const float* __restrict__ tab,
                                                  const int* __restrict__ labels,
                                                  float* __restrict__ x0){
  long idx = (long)blockIdx.x*256 + threadIdx.x;   // BT*768
  if (idx >= 1536L*768) return;
  int m = (int)(idx/768), d = (int)(idx%768);
  x0[idx] = tab[(long)labels[m]*768 + d];
}

// ---------- transpose biaffine 500x500 ----------
__global__ __launch_bounds__(256) void trans_sq(const float* __restrict__ w,
                                                float* __restrict__ wt){
  int idx = blockIdx.x*256 + threadIdx.x;          // 250,000
  if (idx >= 250000) return;
  int j = idx/500, i = idx%500;
  wt[idx] = w[(long)i*500 + j];                    // wt[j][i] = w[i][j]
}

// ---------- generic fp32 GEMM: C[m,n] = sum_k A[m,k]*B[n,k] (+bias, leaky) ----------
__global__ __launch_bounds__(256) void gemm_abt(const float* __restrict__ A,
                                                const float* __restrict__ Bm,
                                                float* __restrict__ C,
                                                const float* __restrict__ bias,
                                                int M, int N, int K,
                                                long sA, long sB, long sC, int leaky){
  A  += (long)blockIdx.z * sA;
  Bm += (long)blockIdx.z * sB;
  C  += (long)blockIdx.z * sC;
  __shared__ float As[16][68];
  __shared__ float Bs[16][68];
  int tid = threadIdx.x;
  int tx = tid & 15, ty = tid >> 4;
  int m0 = blockIdx.x * 64, n0 = blockIdx.y * 64;
  int lrow = tid >> 2, lc = (tid & 3) * 4;
  float acc[4][4] = {};
  for (int k0 = 0; k0 < K; k0 += 16) {
    #pragma unroll
    for (int u = 0; u < 4; u++) {
      int k = k0 + lc + u;
      int am = m0 + lrow;
      As[lc+u][lrow] = (am < M && k < K) ? A[(long)am*K + k] : 0.f;
      int bn = n0 + lrow;
      Bs[lc+u][lrow] = (bn < N && k < K) ? Bm[(long)bn*K + k] : 0.f;
    }
    __syncthreads();
    #pragma unroll
    for (int kk = 0; kk < 16; kk++) {
      float a[4], bb[4];
      #pragma unroll
      for (int u=0;u<4;u++){ a[u]=As[kk][ty*4+u]; bb[u]=Bs[kk][tx*4+u]; }
      #pragma unroll
      for (int i=0;i<4;i++)
        #pragma unroll
        for (int j=0;j<4;j++) acc[i][j] = fmaf(a[i], bb[j], acc[i][j]);
    }
    __syncthreads();
  }
  #pragma unroll
  for (int i=0;i<4;i++){
    int m = m0 + ty*4 + i;
    if (m >= M) continue;
    #pragma unroll
    for (int j=0;j<4;j++){
      int n = n0 + tx*4 + j;
      if (n >= N) continue;
      float v = acc[i][j];
      if (bias) v += bias[n];
      if (leaky) v = v > 0.f ? v : 0.1f*v;
      C[(long)m*N + n] = v;
    }
  }
}

// ---------- weight-stationary grid-synced LSTM (one layer, 96 steps) ----------
__global__ __launch_bounds__(128) void lstm_grid(const float* __restrict__ G,
                                                 const float* __restrict__ whh,
                                                 float* __restrict__ xout,
                                                 float* __restrict__ hbufG,
                                                 unsigned* __restrict__ flags,
                                                 int layer){
  __shared__ float Wl[32*404];    // 32 rows x 400 (+4 pad) = 51.7KB
  __shared__ float hl[16*404];    // 16 bat x 400 (+4 pad)  = 25.9KB
  __shared__ float gb[32][17];    // gate dots [row][bat]
  int tid = threadIdx.x;
  int bid = blockIdx.x;
  int dir = bid / 50;
  int slice = bid % 50;
  int jj0 = slice * 8;
  const float* whhL = whh + (size_t)(layer*2 + dir)*1600*400;
  for (int i = tid; i < 3200; i += 128){        // 32 rows * 100 float4
    int r = i/100, k4 = i%100;
    int g = r>>3, jjr = r&7;
    float4 v = *(const float4*)(whhL + (size_t)(g*400 + jj0 + jjr)*400 + k4*4);
    *(float4*)&Wl[r*404 + k4*4] = v;
  }
  for (int i = tid; i < 16*404; i += 128) hl[i] = 0.f;
  int ks   = (tid>>4)&3;                        // k-chunk 0..3 (100 k each)
  int tile = (tid & 15) | ((tid>>6)<<4);        // 0..31
  int batg = tile & 3, rowg = tile >> 2;        // 4 bats x 4 rows per tile
  int ebat = tid >> 3, ejj = tid & 7;           // epilogue: one (bat,jj) per thread
  const float* hb = hl + batg*4*404;
  const float* wb = Wl + rowg*4*404;
  const float* gbase = G + (size_t)ebat*96*3200 + dir*1600 + jj0 + ejj;
  float* xo = xout + (size_t)ebat*96*800 + dir*400 + jj0 + ejj;
  float c = 0.f;
  int t0 = dir ? 95 : 0;
  const float* gp0 = gbase + (size_t)t0*3200;
  float g0 = gp0[0], g1 = gp0[400], g2 = gp0[800], g3 = gp0[1200];
  __syncthreads();
  for (int s = 0; s < 96; s++){
    int t = dir ? 95 - s : s;
    float acc[4][4] = {};
    int kend = ks*25 + 25;
    #pragma unroll 5
    for (int k4 = ks*25; k4 < kend; ++k4){
      float4 h0 = *(const float4*)&hb[0*404 + k4*4];
      float4 h1 = *(const float4*)&hb[1*404 + k4*4];
      float4 h2 = *(const float4*)&hb[2*404 + k4*4];
      float4 h3 = *(const float4*)&hb[3*404 + k4*4];
      float4 w0 = *(const float4*)&wb[0*404 + k4*4];
      float4 w1 = *(const float4*)&wb[1*404 + k4*4];
      float4 w2 = *(const float4*)&wb[2*404 + k4*4];
      float4 w3 = *(const float4*)&wb[3*404 + k4*4];
      #pragma unroll
      for (int bi=0; bi<4; bi++){
        float4 hq = bi==0?h0: bi==1?h1: bi==2?h2: h3;
        #pragma unroll
        for (int ri=0; ri<4; ri++){
          float4 wq = ri==0?w0: ri==1?w1: ri==2?w2: w3;
          acc[bi][ri] = fmaf(hq.x,wq.x, fmaf(hq.y,wq.y,
                        fmaf(hq.z,wq.z, fmaf(hq.w,wq.w, acc[bi][ri]))));
        }
      }
    }
    #pragma unroll
    for (int bi=0; bi<4; bi++)
      #pragma unroll
      for (int ri=0; ri<4; ri++){
        float v = acc[bi][ri];
        v += __shfl_xor(v, 16);
        v += __shfl_xor(v, 32);
        acc[bi][ri] = v;
      }
    if (ks == 0){
      #pragma unroll
      for (int ri=0; ri<4; ri++)
        #pragma unroll
        for (int bi=0; bi<4; bi++)
          gb[rowg*4+ri][batg*4+bi] = acc[bi][ri];
    }
    __syncthreads();
    float ai = gb[     ejj][ebat] + g0;
    float af = gb[ 8 + ejj][ebat] + g1;
    float ag = gb[16 + ejj][ebat] + g2;
    float ao = gb[24 + ejj][ebat] + g3;
    c = sigf(af)*c + sigf(ai)*tanhf(ag);
    float hv = sigf(ao)*tanhf(c);
    int par = s & 1;
    agent_st(&hbufG[((size_t)(par*2 + dir)*16 + ebat)*400 + jj0 + ejj], hv);
    xo[(size_t)t*800] = hv;
    if (s < 95){
      unsigned target = (unsigned)(layer*95 + s + 1);
      __syncthreads();    // every wave: vmcnt(0) -> h stores ack'd at coherent pt
      if (tid == 0)
        __hip_atomic_store(&flags[bid*16], target, __ATOMIC_RELAXED,
                           __HIP_MEMORY_SCOPE_AGENT);
      int tn = dir ? 94 - s : s + 1;
      const float* gp = gbase + (size_t)tn*3200;
      g0 = gp[0]; g1 = gp[400]; g2 = gp[800]; g3 = gp[1200];
      if (tid < NBLK_LSTM){
        while (__hip_atomic_load(&flags[tid*16], __ATOMIC_RELAXED,
                                 __HIP_MEMORY_SCOPE_AGENT) < target){
          __builtin_amdgcn_s_sleep(1);
        }
      }
      __syncthreads();
      const float* hsrc = hbufG + (size_t)(par*2 + dir)*6400;
      float hA[16], hB[16], hC[16], hT0, hT1;
      #pragma unroll
      for (int bat = 0; bat < 16; bat++){
        hA[bat] = agent_ld(hsrc + bat*400 + tid);
        hB[bat] = agent_ld(hsrc + bat*400 + 128 + tid);
        hC[bat] = agent_ld(hsrc + bat*400 + 256 + tid);
      }
      hT0 = agent_ld(hsrc + (tid>>4)*400 + 384 + (tid&15));
      hT1 = agent_ld(hsrc + ((tid+128)>>4)*400 + 384 + (tid&15));
      #pragma unroll
      for (int bat = 0; bat < 16; bat++){
        hl[bat*404 + tid]       = hA[bat];
        hl[bat*404 + 128 + tid] = hB[bat];
        hl[bat*404 + 256 + tid] = hC[bat];
      }
      hl[(tid>>4)*404 + 384 + (tid&15)] = hT0;
      hl[((tid+128)>>4)*404 + 384 + (tid&15)] = hT1;
      __syncthreads();
    }
  }
}

// ---------- log_softmax over last axis of s_arc, write transposed p ----------
__global__ __launch_bounds__(256) void softmax_p(const float* __restrict__ sarc,
                                                 float* __restrict__ p){
  int row  = blockIdx.x*4 + (threadIdx.x >> 6);  // 0..1535  (b,x)
  int lane = threadIdx.x & 63;
  int b = row/96, x = row%96;
  const float* s = sarc + (long)(b*96 + x)*96;
  float v1 = s[lane];
  float v2 = (lane+64 < 96) ? s[lane+64] : -INFINITY;
  float mx = wred_max(fmaxf(v1,v2));
  float sm = wred_sum(__expf(v1-mx) + __expf(v2-mx));
  float lse = mx + __logf(sm);
  float* pr = p + (long)b*9216;
  pr[lane*96 + x] = v1 - lse;
  if (lane+64 < 96) pr[(lane+64)*96 + x] = v2 - lse;
}

// ---------- best_score ----------
__global__ __launch_bounds__(128) void best_kern(const float* __restrict__ p,
                                                 const float* __restrict__ multinomial,
                                                 const int* __restrict__ labels,
                                                 const int* __restrict__ heads,
                                                 float* __restrict__ best){
  int b = blockIdx.x, tid = threadIdx.x;
  float acc = 0.f;
  for (int ti = tid; ti < 95; ti += 128) {
    int y = heads[b*95 + ti];
    int x = ti + 1;
    acc += p[(long)b*9216 + y*96 + x]
         + multinomial[(long)labels[b*96 + y]*64 + labels[b*96 + x]];
  }
  acc = wred_sum(acc);
  __shared__ float tmp[2];
  if ((tid & 63) == 0) tmp[tid >> 6] = acc;
  __syncthreads();
  if (tid == 0) best[b] = tmp[0] + tmp[1];
}

// ---------- Eisner inside, task-parallel (r7) ----------
// Storage (all 96x97, diag shared):
//   Cp : upper C_r[i][j]; lower Cp[a][b] = C_l[b][a]; diag 0
//   Ipp: upper I_r[i][j]; lower Ipp[a][b] = I_l[b][a]
//   Xp : upper Xp[a][b] = C_l[a][b]; lower Xp[a][b] = C_r[b][a]; diag 0
//   Pl : p[i][j]
// Per width w: phase A (inc -> I_r,I_l), barrier, phase B (cr+cl as one
// uniform task loop), barrier. All LSE operands are contiguous row reads:
//   inc: Cp[i][i+r]        + Cp[j][i+1+r]     r=0..w-1
//   cr : Ipp[i][i+1+r]     + Xp[j][i+1+r]     r=0..w-1 (r=w-1: Ipp=ir, Xp diag=0)
//   cl : Xp[i][i+r]        + Ipp[j][i+r]      r=0..w-1 (r=0: Xp diag=0, Ipp=il)
// 8-lane groups; term r = lane + 8k, k<12 register-buffered (static unroll).
__global__ __launch_bounds__(1024) void inside_kern(const float* __restrict__ p,
                                                    float* __restrict__ part){
  __shared__ float Cp[96][97];
  __shared__ float Ipp[96][97];
  __shared__ float Xp[96][97];
  __shared__ float Pl[96][97];
  int b = blockIdx.x;
  const float* pB = p + (long)b*9216;
  int tid = threadIdx.x;
  for (int idx = tid; idx < 96*97; idx += 1024) {
    int row = idx/97, col = idx%97;
    float d = (row == col) ? 0.f : -1e9f;
    Cp[row][col] = d;
    Xp[row][col] = d;
    Ipp[row][col] = -1e9f;
  }
  for (int idx = tid; idx < 9216; idx += 1024)
    Pl[idx/96][idx%96] = pB[idx];
  __syncthreads();
  int g = tid >> 3, l = tid & 7;   // 128 groups of 8 lanes
  for (int w = 1; w < 96; w++){
    int n = 96 - w;
    // ---- phase A: inc ----
    if (g < n){
      int i = g, j = i + w;
      const float* pa  = &Cp[i][i];
      const float* pb2 = &Cp[j][i+1];
      float vb[12]; float m = -1e30f;
      #pragma unroll
      for (int k = 0; k < 12; k++){
        vb[k] = -1e30f;
        if (k*8 < w){                     // uniform skip
          int r = l + k*8;
          if (r < w){ float v = pa[r] + pb2[r]; vb[k] = v; m = fmaxf(m, v); }
        }
      }
      m = fmaxf(m, __shfl_xor(m,1));
      m = fmaxf(m, __shfl_xor(m,2));
      m = fmaxf(m, __shfl_xor(m,4));
      float s = 0.f;
      #pragma unroll
      for (int k = 0; k < 12; k++){
        if (k*8 < w) s += __expf(vb[k] - m);
      }
      s += __shfl_xor(s,1); s += __shfl_xor(s,2); s += __shfl_xor(s,4);
      if (l == 0){
        float inc = m + __logf(s);
        Ipp[i][j] = inc + Pl[i][j];
        Ipp[j][i] = inc + Pl[j][i];
      }
    }
    __syncthreads();
    // ---- phase B: cr (task<n) and cl (task>=n), uniform code ----
    for (int task = g; task < 2*n; task += 128){
      int typ = task < n ? 1 : 0;        // 1 = cr, 0 = cl
      int i = typ ? task : task - n;
      int j = i + w;
      const float* pa  = typ ? &Ipp[i][i+1] : &Xp[i][i];
      const float* pb2 = typ ? &Xp[j][i+1]  : &Ipp[j][i];
      float vb[12]; float m = -1e30f;
      #pragma unroll
      for (int k = 0; k < 12; k++){
        vb[k] = -1e30f;
        if (k*8 < w){
          int r = l + k*8;
          if (r < w){ float v = pa[r] + pb2[r]; vb[k] = v; m = fmaxf(m, v); }
        }
      }
      m = fmaxf(m, __shfl_xor(m,1));
      m = fmaxf(m, __shfl_xor(m,2));
      m = fmaxf(m, __shfl_xor(m,4));
      float s = 0.f;
      #pragma unroll
      for (int k = 0; k < 12; k++){
        if (k*8 < w) s += __expf(vb[k] - m);
      }
      s += __shfl_xor(s,1); s += __shfl_xor(s,2); s += __shfl_xor(s,4);
      if (l == 0){
        float res = m + __logf(s);
        if (typ){ Cp[i][j] = res; Xp[j][i] = res; }
        else    { Cp[j][i] = res; Xp[i][j] = res; }
      }
    }
    __syncthreads();
  }
  if (tid == 0) part[b] = Cp[0][95];
}

// ---------- final mean ----------
__global__ __launch_bounds__(64) void final_kern(const float* __restrict__ part,
                                                 const float* __restrict__ best,
                                                 float* __restrict__ out){
  int lane = threadIdx.x;
  float v = (lane < 16) ? part[lane] - best[lane] : 0.f;
  v = wred_sum(v);
  if (lane == 0) out[0] = v * (1.f/16.f);
}

extern "C" void kernel_launch(void* const* d_in, const int* in_sizes, int n_in,
                              void* d_out, int out_size, void* d_ws, size_t ws_size,
                              hipStream_t stream) {
  const float* emb   = (const float*)d_in[0];
  const float* multi = (const float*)d_in[1];
  const float* wih0  = (const float*)d_in[2];
  const float* wih   = (const float*)d_in[3];
  const float* whh   = (const float*)d_in[4];
  const float* bias  = (const float*)d_in[5];
  const float* mhw   = (const float*)d_in[6];
  const float* mhb   = (const float*)d_in[7];
  const float* mdw   = (const float*)d_in[8];
  const float* mdb   = (const float*)d_in[9];
  const float* biaf  = (const float*)d_in[10];
  const int*   labels= (const int*)d_in[11];
  const int*   heads = (const int*)d_in[12];
  float* out = (float*)d_out;

  float* ws = (float*)d_ws;
  size_t off = 0;
  auto alloc = [&](size_t n){ float* q = ws + off; off += n; return q; };
  float* G    = alloc(1536L*3200);
  float* x0   = alloc(1536L*768);
  float* xA   = alloc(1536L*800);
  float* xB   = alloc(1536L*800);
  float* WTb  = alloc(500L*500);
  float* arcH = alloc(1536L*500);
  float* arcD = alloc(1536L*500);
  float* tmp  = alloc(1536L*500);
  float* sarc = alloc(16L*96*96);
  float* pbuf = alloc(16L*96*96);
  float* hbufG= alloc(2L*2*16*400);
  unsigned* flags = (unsigned*)alloc(NBLK_LSTM*16);
  float* part = alloc(16);
  float* best = alloc(16);
  (void)ws_size; (void)in_sizes; (void)n_in; (void)out_size;

  hipMemsetAsync(flags, 0, NBLK_LSTM*16*sizeof(unsigned), stream);

  embed_kern<<<(1536*768)/256, 256, 0, stream>>>(emb, labels, x0);
  trans_sq<<<(250000+255)/256, 256, 0, stream>>>(biaf, WTb);

  const float* xin = x0;
  float* xout = xA;
  for (int l = 0; l < 3; l++) {
    int Kd = (l==0) ? 768 : 800;
    const float* W = (l==0) ? wih0 : wih + (size_t)(l-1)*2*1600*800;
    dim3 gp(24, 50, 1);
    gemm_abt<<<gp, 256, 0, stream>>>(xin, W, G, bias + l*3200, 1536, 3200, Kd, 0,0,0, 0);
    lstm_grid<<<NBLK_LSTM, 128, 0, stream>>>(G, whh, xout, hbufG, flags, l);
    xin = xout;
    xout = (l==0) ? xB : xA;
  }
  // xin == xA (l0:x0->xA, l1:xA->xB, l2:xB->xA)
  dim3 gm(24, 8, 1);
  gemm_abt<<<gm, 256, 0, stream>>>(xin,  mhw, arcH, mhb, 1536, 500, 800, 0,0,0, 1);
  gemm_abt<<<gm, 256, 0, stream>>>(xin,  mdw, arcD, mdb, 1536, 500, 800, 0,0,0, 1);
  gemm_abt<<<gm, 256, 0, stream>>>(arcD, WTb, tmp, nullptr, 1536, 500, 500, 0,0,0, 0);
  dim3 gs(2, 2, 16);
  gemm_abt<<<gs, 256, 0, stream>>>(tmp, arcH, sarc, nullptr, 96, 96, 500,
                                   96L*500, 96L*500, 96L*96, 0);
  softmax_p<<<384, 256, 0, stream>>>(sarc, pbuf);
  best_kern<<<16, 128, 0, stream>>>(pbuf, multi, labels, heads, best);
  inside_kern<<<16, 1024, 0, stream>>>(pbuf, part);
  final_kern<<<1, 64, 0, stream>>>(part, best, out);
}